// Round 4
// baseline (192.743 us; speedup 1.0000x reference)
//
#include <hip/hip_runtime.h>
#include <hip/hip_bf16.h>
#include <stdint.h>

#define B_ 4
#define T_ 2048
#define F_ 512
#define H_ 8
#define DK_ 64
#define BT_ (B_*T_)   // 8192

typedef short bf16x8 __attribute__((ext_vector_type(8)));
typedef short s16x4 __attribute__((ext_vector_type(4)));
typedef float f32x4 __attribute__((ext_vector_type(4)));
typedef float f32x16 __attribute__((ext_vector_type(16)));

__device__ __forceinline__ unsigned short f2bf(float f) {
  union { float f; unsigned u; } v; v.f = f;
  return (unsigned short)((v.u + 0x7fffu + ((v.u >> 16) & 1u)) >> 16);
}

__device__ __forceinline__ unsigned cvtpk(float lo, float hi) {
  unsigned w;
  asm("v_cvt_pk_bf16_f32 %0, %1, %2" : "=v"(w) : "v"(lo), "v"(hi));
  return w;
}

__device__ __forceinline__ void gload_lds16(const void* g, void* l) {
  __builtin_amdgcn_global_load_lds((const __attribute__((address_space(1))) void*)g,
                                   (__attribute__((address_space(3))) void*)l, 16, 0, 0);
}

// ---------------- weight conversion fp32 -> bf16, plus mask -> float addend ----------------
__global__ void convert_w(const float* __restrict__ wq, const float* __restrict__ wk,
                          const float* __restrict__ wv, const float* __restrict__ wo,
                          const int* __restrict__ mask,
                          unsigned short* __restrict__ dst, float* __restrict__ maskf) {
  const int seg = blockIdx.y;
  if (seg == 4) {
    if (blockIdx.x < 4) {   // 4 blocks * 256 * 8 = 8192 = B*T exact
      const int idx = (blockIdx.x * 256 + threadIdx.x) * 8;
      int4 a = *(const int4*)(mask + idx);
      int4 b = *(const int4*)(mask + idx + 4);
      float4 fa, fb;
      fa.x = a.x ? 0.0f : -__builtin_inff(); fa.y = a.y ? 0.0f : -__builtin_inff();
      fa.z = a.z ? 0.0f : -__builtin_inff(); fa.w = a.w ? 0.0f : -__builtin_inff();
      fb.x = b.x ? 0.0f : -__builtin_inff(); fb.y = b.y ? 0.0f : -__builtin_inff();
      fb.z = b.z ? 0.0f : -__builtin_inff(); fb.w = b.w ? 0.0f : -__builtin_inff();
      *(float4*)(maskf + idx) = fa;
      *(float4*)(maskf + idx + 4) = fb;
    }
    return;
  }
  const float* src = seg == 0 ? wq : (seg == 1 ? wk : (seg == 2 ? wv : wo));
  unsigned short* out = dst + (size_t)seg * F_ * F_;
  const int idx = (blockIdx.x * 256 + threadIdx.x) * 8;   // 128 blocks * 256 * 8 = 262144 exact
  float4 a = *(const float4*)(src + idx);
  float4 b = *(const float4*)(src + idx + 4);
  union { unsigned w[4]; bf16x8 v; } t;
  t.w[0] = cvtpk(a.x, a.y); t.w[1] = cvtpk(a.z, a.w);
  t.w[2] = cvtpk(b.x, b.y); t.w[3] = cvtpk(b.z, b.w);
  *(bf16x8*)(out + idx) = t.v;
}

// ---------------- GEMM: C = (A @ W^T + bias) * sc ----------------
template <bool A_F32, bool OUT_F32>
__global__ __launch_bounds__(256, 2) void gemm_bt(
    const float* __restrict__ af0, const float* __restrict__ af1, const float* __restrict__ af2,
    const unsigned short* __restrict__ Abf,
    const unsigned short* __restrict__ Wbase,
    const float* __restrict__ b0, const float* __restrict__ b1, const float* __restrict__ b2,
    unsigned short* __restrict__ outb, float* __restrict__ outf, float scale0) {
  const int p = blockIdx.z;
  const float* Af = (p == 0) ? af0 : (p == 1 ? af1 : af2);
  const unsigned short* W = Wbase + (size_t)p * F_ * F_;
  const float* bias = (p == 0) ? b0 : (p == 1 ? b1 : b2);
  const float sc = (p == 0) ? scale0 : 1.0f;

  const int tid = threadIdx.x;
  const int wid = tid >> 6, lane = tid & 63;
  const int lr = lane & 15, lg = lane >> 4;
  const int wr = wid >> 1, wc = wid & 1;
  const int m0 = blockIdx.x * 128, n0 = blockIdx.y * 128;

  __shared__ __align__(16) unsigned short As[128 * 32];
  __shared__ __align__(16) unsigned short Bs[128 * 32];

  f32x4 acc[4][4] = {};

  for (int k0 = 0; k0 < F_; k0 += 32) {
#pragma unroll
    for (int i = 0; i < 2; ++i) {
      const int ch = i * 256 + tid;
      const int r = ch >> 2, s = ch & 3;
      if constexpr (A_F32) {
        const float* src = Af + (size_t)(m0 + r) * F_ + k0 + s * 8;
        float4 x0 = *(const float4*)src;
        float4 x1 = *(const float4*)(src + 4);
        union { unsigned w[4]; bf16x8 v; } t;
        t.w[0] = cvtpk(x0.x, x0.y); t.w[1] = cvtpk(x0.z, x0.w);
        t.w[2] = cvtpk(x1.x, x1.y); t.w[3] = cvtpk(x1.z, x1.w);
        *(bf16x8*)&As[ch * 8] = t.v;
      } else {
        gload_lds16(Abf + (size_t)(m0 + r) * F_ + k0 + s * 8, &As[(i * 256 + wid * 64) * 8]);
      }
      gload_lds16(W + (size_t)(n0 + r) * F_ + k0 + s * 8, &Bs[(i * 256 + wid * 64) * 8]);
    }
    __syncthreads();

    bf16x8 af[4], bf[4];
#pragma unroll
    for (int m = 0; m < 4; ++m)
      af[m] = *(const bf16x8*)&As[(wr * 64 + m * 16 + lr) * 32 + lg * 8];
#pragma unroll
    for (int n = 0; n < 4; ++n)
      bf[n] = *(const bf16x8*)&Bs[(wc * 64 + n * 16 + lr) * 32 + lg * 8];
#pragma unroll
    for (int m = 0; m < 4; ++m)
#pragma unroll
      for (int n = 0; n < 4; ++n)
        acc[m][n] = __builtin_amdgcn_mfma_f32_16x16x32_bf16(af[m], bf[n], acc[m][n], 0, 0, 0);
    __syncthreads();
  }

  unsigned short* ob = OUT_F32 ? nullptr : outb + (size_t)p * BT_ * F_;
#pragma unroll
  for (int n = 0; n < 4; ++n) {
    const int col = n0 + wc * 64 + n * 16 + lr;
    const float bv = bias[col];
#pragma unroll
    for (int m = 0; m < 4; ++m) {
      const int rbase = m0 + wr * 64 + m * 16 + lg * 4;
#pragma unroll
      for (int j = 0; j < 4; ++j) {
        const float v = (acc[m][n][j] + bv) * sc;
        if constexpr (OUT_F32) outf[(size_t)(rbase + j) * F_ + col] = v;
        else                   ob[(size_t)(rbase + j) * F_ + col] = f2bf(v);
      }
    }
  }
}

// ---------------- V transpose: (B,T,F)-per-head -> [BH][DK][T] ----------------
__global__ void transpose_v(const unsigned short* __restrict__ Vp, unsigned short* __restrict__ Vt) {
  const int bh = blockIdx.y, b = bh >> 3, h = bh & 7;
  const int t0 = blockIdx.x * 64;
  const int tid = threadIdx.x;
  __shared__ __align__(16) unsigned short tile[64][72];

#pragma unroll
  for (int i = 0; i < 2; ++i) {
    const int ch = i * 256 + tid;          // 512 chunks of 8
    const int t = ch >> 3, s = ch & 7;
    bf16x8 v = *(const bf16x8*)(Vp + (size_t)(b * T_ + t0 + t) * F_ + h * DK_ + s * 8);
    *(bf16x8*)&tile[t][s * 8] = v;
  }
  __syncthreads();
#pragma unroll
  for (int i = 0; i < 2; ++i) {
    const int ch = i * 256 + tid;
    const int d = ch >> 3, s = ch & 7;
    union { unsigned short u[8]; bf16x8 v; } r;
#pragma unroll
    for (int j = 0; j < 8; ++j) r.u[j] = tile[s * 8 + j][d];
    *(bf16x8*)(Vt + ((size_t)bh * DK_ + d) * T_ + t0 + s * 8) = r.v;
  }
}

// ---------------- flash attention, swapped-operand 32x32, optional kv-split ----------------
// 4 waves x 32 q-rows; KV tile 64, double-buffered. S^T = mfma(K,Q) -> lane owns one q-row.
// Softmax in-register; P repack via cvt_pk + permlane32_swap. O^T = mfma(V^T, P^T).
// NSPLIT=2: each z-block does half the kv range, writes fp32 partial O + (m,l).
template <int NSPLIT>
__global__ __launch_bounds__(256, 4) void attn_kernel(
    const unsigned short* __restrict__ Qp,
    const unsigned short* __restrict__ Kp,
    const unsigned short* __restrict__ Vt,
    const float* __restrict__ maskf,
    unsigned short* __restrict__ X,
    float* __restrict__ Opart,
    float2* __restrict__ ml) {
  const int tid = threadIdx.x, wid = tid >> 6, lane = tid & 63;
  const int la = lane & 31, hi = lane >> 5;
  const int bh = blockIdx.y, b = bh >> 3, h = bh & 7;
  const int z = (NSPLIT == 2) ? blockIdx.z : 0;
  const int qrow = blockIdx.x * 128 + wid * 32 + la;
  const int kvbase = z * (T_ / NSPLIT);
  const int ntiles = T_ / (64 * NSPLIT);

  __shared__ __align__(16) unsigned short Ks[2][64 * 64];  // [kv][dk], 16B-slot XOR swizzle
  __shared__ __align__(16) unsigned short Vs[2][64 * 64];  // [d][kv], swizzled
  __shared__ __align__(16) float Ms[2][64];                // mask addend

  // Q B-fragments (held for whole block): B[k=kk*16+hi*8+e][col=la]
  bf16x8 qf[4];
#pragma unroll
  for (int kk = 0; kk < 4; ++kk)
    qf[kk] = *(const bf16x8*)(Qp + (size_t)(b * T_ + qrow) * F_ + h * DK_ + kk * 16 + hi * 8);

  f32x16 oacc[2] = {};
  float mrun = -1e30f, lrun = 0.0f;

  auto stage = [&](int buf, int kv0) {
#pragma unroll
    for (int i = 0; i < 2; ++i) {
      const int ch = i * 256 + tid;
      const int r = ch >> 3, s = ch & 7;
      gload_lds16(Kp + (size_t)(b * T_ + kv0 + r) * F_ + h * DK_ + ((s ^ (r & 7)) * 8),
                  &Ks[buf][(i * 256 + wid * 64) * 8]);
      gload_lds16(Vt + ((size_t)bh * DK_ + r) * T_ + kv0 + ((s ^ (r & 7)) * 8),
                  &Vs[buf][(i * 256 + wid * 64) * 8]);
    }
    if (wid == 0 && lane < 16)
      gload_lds16(maskf + b * T_ + kv0 + lane * 4, &Ms[buf][0]);
  };

  stage(0, kvbase);
  __syncthreads();

  for (int t = 0; t < ntiles; ++t) {
    const int cur = t & 1;
    if (t < ntiles - 1) stage(cur ^ 1, kvbase + (t + 1) * 64);

    // K A-fragments: A[row=kv=n*32+la][k=kk*16+hi*8+e]
    bf16x8 kf0[4], kf1[4];
#pragma unroll
    for (int kk = 0; kk < 4; ++kk) {
      kf0[kk] = *(const bf16x8*)&Ks[cur][la * 64 + (((2 * kk + hi) ^ (la & 7)) * 8)];
      kf1[kk] = *(const bf16x8*)&Ks[cur][(32 + la) * 64 + (((2 * kk + hi) ^ (la & 7)) * 8)];
    }
    // mask addend, broadcast reads
    f32x4 mfv[2][4];
#pragma unroll
    for (int n = 0; n < 2; ++n)
#pragma unroll
      for (int g = 0; g < 4; ++g)
        mfv[n][g] = *(const f32x4*)&Ms[cur][n * 32 + 8 * g + 4 * hi];

    // S^T = K · Q^T  (col = q-row = la, row = kv)
    f32x16 s0 = {}, s1 = {};
    __builtin_amdgcn_s_setprio(1);
#pragma unroll
    for (int kk = 0; kk < 4; ++kk) {
      s0 = __builtin_amdgcn_mfma_f32_32x32x16_bf16(kf0[kk], qf[kk], s0, 0, 0, 0);
      s1 = __builtin_amdgcn_mfma_f32_32x32x16_bf16(kf1[kk], qf[kk], s1, 0, 0, 0);
    }
    __builtin_amdgcn_s_setprio(0);

    // row max (raw/unmasked is a valid overestimate)
    float mx[16];
#pragma unroll
    for (int r = 0; r < 16; ++r) mx[r] = fmaxf(s0[r], s1[r]);
#pragma unroll
    for (int st = 8; st > 0; st >>= 1)
#pragma unroll
      for (int r = 0; r < st; ++r) mx[r] = fmaxf(mx[r], mx[r + st]);
    const float rmx = fmaxf(mx[0], __shfl_xor(mx[0], 32, 64));

    // defer-max (T13): rescale only when max grew beyond THR=8 (exp2 domain)
    if (!__all(rmx <= mrun + 8.0f)) {
      const float mnew = fmaxf(mrun, rmx);
      const float alpha = __builtin_amdgcn_exp2f(mrun - mnew);
      lrun *= alpha;
#pragma unroll
      for (int m = 0; m < 2; ++m)
#pragma unroll
        for (int r = 0; r < 16; ++r) oacc[m][r] *= alpha;
      mrun = mnew;
    }

    // P = exp2(S + mask - m)
    float p0[16], p1[16];
#pragma unroll
    for (int r = 0; r < 16; ++r) {
      p0[r] = __builtin_amdgcn_exp2f((s0[r] + mfv[0][r >> 2][r & 3]) - mrun);
      p1[r] = __builtin_amdgcn_exp2f((s1[r] + mfv[1][r >> 2][r & 3]) - mrun);
    }
    float sm[16];
#pragma unroll
    for (int r = 0; r < 16; ++r) sm[r] = p0[r] + p1[r];
#pragma unroll
    for (int st = 8; st > 0; st >>= 1)
#pragma unroll
      for (int r = 0; r < st; ++r) sm[r] += sm[r + st];
    lrun += sm[0] + __shfl_xor(sm[0], 32, 64);

    // pack P pairs to bf16 words; exchange halves via permlane32_swap:
    // after swap(xE, xO): xE = low-words (w0,w1), xO = high-words (w2,w3)
    unsigned lowr[2][2][2], uppr[2][2][2];
#pragma unroll
    for (int n = 0; n < 2; ++n)
#pragma unroll
      for (int gg = 0; gg < 2; ++gg)
#pragma unroll
        for (int hh = 0; hh < 2; ++hh) {
          const float* ps = (n == 0) ? p0 : p1;
          unsigned xE = cvtpk(ps[4 * (2 * gg) + 2 * hh], ps[4 * (2 * gg) + 2 * hh + 1]);
          unsigned xO = cvtpk(ps[4 * (2 * gg + 1) + 2 * hh], ps[4 * (2 * gg + 1) + 2 * hh + 1]);
          asm("v_permlane32_swap_b32 %0, %1" : "+v"(xE), "+v"(xO));
          lowr[n][gg][hh] = xE;
          uppr[n][gg][hh] = xO;
        }

    // O^T += V^T · P^T
#pragma unroll
    for (int kt = 0; kt < 4; ++kt) {
      const int n = kt >> 1, gg = kt & 1;
      union { unsigned w[4]; bf16x8 v; } pf;
      pf.w[0] = lowr[n][gg][0]; pf.w[1] = lowr[n][gg][1];
      pf.w[2] = uppr[n][gg][0]; pf.w[3] = uppr[n][gg][1];
      __builtin_amdgcn_s_setprio(1);
#pragma unroll
      for (int m = 0; m < 2; ++m) {
        bf16x8 vfr = *(const bf16x8*)&Vs[cur][(m * 32 + la) * 64 + (((2 * kt + hi) ^ (la & 7)) * 8)];
        oacc[m] = __builtin_amdgcn_mfma_f32_32x32x16_bf16(vfr, pf.v, oacc[m], 0, 0, 0);
      }
      __builtin_amdgcn_s_setprio(0);
    }
    __syncthreads();   // drains vmcnt: next tile staged; buf[cur] reads all done
  }

  if constexpr (NSPLIT == 1) {
    const float inv = 1.0f / fmaxf(lrun, 1e-37f);
#pragma unroll
    for (int m = 0; m < 2; ++m)
#pragma unroll
      for (int g = 0; g < 4; ++g) {
        union { unsigned short u[4]; s16x4 v; } ov;
#pragma unroll
        for (int j = 0; j < 4; ++j) ov.u[j] = f2bf(oacc[m][4 * g + j] * inv);
        *(s16x4*)(X + (size_t)(b * T_ + qrow) * F_ + h * DK_ + m * 32 + 8 * g + 4 * hi) = ov.v;
      }
  } else {
    const int r = b * T_ + qrow;
    if (hi == 0) ml[(size_t)z * BT_ * H_ + (size_t)r * H_ + h] = float2{mrun, lrun};
    float* op = Opart + (size_t)z * BT_ * F_ + (size_t)r * F_ + h * DK_;
#pragma unroll
    for (int m = 0; m < 2; ++m)
#pragma unroll
      for (int g = 0; g < 4; ++g) {
        f32x4 st;
#pragma unroll
        for (int j = 0; j < 4; ++j) st[j] = oacc[m][4 * g + j];
        *(f32x4*)(op + m * 32 + 8 * g + 4 * hi) = st;
      }
  }
}

// ---------------- merge two kv-split partials -> normalized bf16 X ----------------
__global__ void merge_o(const float* __restrict__ O0, const float* __restrict__ O1,
                        const float2* __restrict__ ml, unsigned short* __restrict__ X) {
  const int gid = blockIdx.x * 256 + threadIdx.x;   // 524288 threads, 8 elems each
  const int r = gid >> 6;
  const int c8 = (gid & 63) * 8;
  const int h = c8 >> 6;
  const float2 a = ml[(size_t)r * H_ + h];
  const float2 bml = ml[(size_t)BT_ * H_ + (size_t)r * H_ + h];
  const float M = fmaxf(a.x, bml.x);
  const float e0 = __builtin_amdgcn_exp2f(a.x - M);
  const float e1 = __builtin_amdgcn_exp2f(bml.x - M);
  const float denom = fmaxf(e0 * a.y + e1 * bml.y, 1e-37f);
  const float w0 = e0 / denom, w1 = e1 / denom;
  const size_t base = (size_t)r * F_ + c8;
  f32x4 x00 = *(const f32x4*)(O0 + base);
  f32x4 x01 = *(const f32x4*)(O0 + base + 4);
  f32x4 x10 = *(const f32x4*)(O1 + base);
  f32x4 x11 = *(const f32x4*)(O1 + base + 4);
  union { unsigned w[4]; bf16x8 v; } t;
  t.w[0] = cvtpk(x00[0] * w0 + x10[0] * w1, x00[1] * w0 + x10[1] * w1);
  t.w[1] = cvtpk(x00[2] * w0 + x10[2] * w1, x00[3] * w0 + x10[3] * w1);
  t.w[2] = cvtpk(x01[0] * w0 + x11[0] * w1, x01[1] * w0 + x11[1] * w1);
  t.w[3] = cvtpk(x01[2] * w0 + x11[2] * w1, x01[3] * w0 + x11[3] * w1);
  *(bf16x8*)(X + base) = t.v;
}

// ---------------- launcher ----------------
extern "C" void kernel_launch(void* const* d_in, const int* in_sizes, int n_in,
                              void* d_out, int out_size, void* d_ws, size_t ws_size,
                              hipStream_t stream) {
  const float* q  = (const float*)d_in[0];
  const float* k  = (const float*)d_in[1];
  const float* v  = (const float*)d_in[2];
  const int* mask = (const int*)d_in[3];
  const float* Wq = (const float*)d_in[4];
  const float* bq = (const float*)d_in[5];
  const float* Wk = (const float*)d_in[6];
  const float* bk = (const float*)d_in[7];
  const float* Wv = (const float*)d_in[8];
  const float* bv = (const float*)d_in[9];
  const float* Wo = (const float*)d_in[10];
  const float* bo = (const float*)d_in[11];
  float* out = (float*)d_out;

  unsigned short* ws = (unsigned short*)d_ws;
  unsigned short* wts  = ws;                               // 4*F*F = 1,048,576 us
  unsigned short* proj = wts + (size_t)4 * F_ * F_;        // 3*BT*F
  unsigned short* vt   = proj + (size_t)3 * BT_ * F_;      // BT*F
  unsigned short* xbuf = vt + (size_t)BT_ * F_;            // BT*F
  float* maskf = (float*)(xbuf + (size_t)BT_ * F_);        // 8448 f32 (B*T + slack)
  float* opart = maskf + 8448;                             // 2*BT*F f32 = 32 MB
  float2* ml   = (float2*)(opart + (size_t)2 * BT_ * F_);  // 2*BT*H float2 = 1 MB
  const size_t NEED_SPLIT = (size_t)((char*)(ml + (size_t)2 * BT_ * H_) - (char*)d_ws);

  const float kQScale = 0.18033688011112042f;  // (1/sqrt(64)) * log2(e)

  convert_w<<<dim3(128, 5, 1), 256, 0, stream>>>(Wq, Wk, Wv, Wo, mask, wts, maskf);
  gemm_bt<true, false><<<dim3(64, 4, 3), 256, 0, stream>>>(
      q, k, v, nullptr, wts, bq, bk, bv, proj, nullptr, kQScale);
  transpose_v<<<dim3(32, 32, 1), 256, 0, stream>>>(proj + (size_t)2 * BT_ * F_, vt);
  if (ws_size >= NEED_SPLIT) {
    attn_kernel<2><<<dim3(16, 32, 2), 256, 0, stream>>>(
        proj, proj + (size_t)BT_ * F_, vt, maskf, nullptr, opart, ml);
    merge_o<<<dim3(2048, 1, 1), 256, 0, stream>>>(opart, opart + (size_t)BT_ * F_, ml, xbuf);
  } else {
    attn_kernel<1><<<dim3(16, 32, 1), 256, 0, stream>>>(
        proj, proj + (size_t)BT_ * F_, vt, maskf, xbuf, nullptr, nullptr);
  }
  gemm_bt<false, true><<<dim3(64, 4, 1), 256, 0, stream>>>(
      nullptr, nullptr, nullptr, xbuf, wts + (size_t)3 * F_ * F_, bo, bo, bo, nullptr, out, 1.0f);
}

// Round 5
// 112.982 us; speedup vs baseline: 1.7060x; 1.7060x over previous
//
#include <hip/hip_runtime.h>
#include <hip/hip_bf16.h>
#include <stdint.h>

#define B_ 4
#define T_ 2048
#define F_ 512
#define H_ 8
#define DK_ 64
#define BT_ (B_*T_)   // 8192

typedef short bf16x8 __attribute__((ext_vector_type(8)));
typedef short s16x4 __attribute__((ext_vector_type(4)));
typedef float f32x4 __attribute__((ext_vector_type(4)));
typedef float f32x16 __attribute__((ext_vector_type(16)));

__device__ __forceinline__ unsigned short f2bf(float f) {
  union { float f; unsigned u; } v; v.f = f;
  return (unsigned short)((v.u + 0x7fffu + ((v.u >> 16) & 1u)) >> 16);
}

__device__ __forceinline__ unsigned cvtpk(float lo, float hi) {
  unsigned w;
  asm("v_cvt_pk_bf16_f32 %0, %1, %2" : "=v"(w) : "v"(lo), "v"(hi));
  return w;
}

__device__ __forceinline__ void gload_lds16(const void* g, void* l) {
  __builtin_amdgcn_global_load_lds((const __attribute__((address_space(1))) void*)g,
                                   (__attribute__((address_space(3))) void*)l, 16, 0, 0);
}

// ---------------- weight conversion fp32 -> bf16, plus mask -> float addend ----------------
__global__ void convert_w(const float* __restrict__ wq, const float* __restrict__ wk,
                          const float* __restrict__ wv, const float* __restrict__ wo,
                          const int* __restrict__ mask,
                          unsigned short* __restrict__ dst, float* __restrict__ maskf) {
  const int seg = blockIdx.y;
  if (seg == 4) {
    if (blockIdx.x < 4) {   // 4 blocks * 256 * 8 = 8192 = B*T exact
      const int idx = (blockIdx.x * 256 + threadIdx.x) * 8;
      int4 a = *(const int4*)(mask + idx);
      int4 b = *(const int4*)(mask + idx + 4);
      float4 fa, fb;
      fa.x = a.x ? 0.0f : -__builtin_inff(); fa.y = a.y ? 0.0f : -__builtin_inff();
      fa.z = a.z ? 0.0f : -__builtin_inff(); fa.w = a.w ? 0.0f : -__builtin_inff();
      fb.x = b.x ? 0.0f : -__builtin_inff(); fb.y = b.y ? 0.0f : -__builtin_inff();
      fb.z = b.z ? 0.0f : -__builtin_inff(); fb.w = b.w ? 0.0f : -__builtin_inff();
      *(float4*)(maskf + idx) = fa;
      *(float4*)(maskf + idx + 4) = fb;
    }
    return;
  }
  const float* src = seg == 0 ? wq : (seg == 1 ? wk : (seg == 2 ? wv : wo));
  unsigned short* out = dst + (size_t)seg * F_ * F_;
  const int idx = (blockIdx.x * 256 + threadIdx.x) * 8;   // 128 blocks * 256 * 8 = 262144 exact
  float4 a = *(const float4*)(src + idx);
  float4 b = *(const float4*)(src + idx + 4);
  union { unsigned w[4]; bf16x8 v; } t;
  t.w[0] = cvtpk(a.x, a.y); t.w[1] = cvtpk(a.z, a.w);
  t.w[2] = cvtpk(b.x, b.y); t.w[3] = cvtpk(b.z, b.w);
  *(bf16x8*)(out + idx) = t.v;
}

// ---------------- GEMM: C = (A @ W^T + bias) * sc ----------------
template <bool A_F32, bool OUT_F32>
__global__ __launch_bounds__(256, 2) void gemm_bt(
    const float* __restrict__ af0, const float* __restrict__ af1, const float* __restrict__ af2,
    const unsigned short* __restrict__ Abf,
    const unsigned short* __restrict__ Wbase,
    const float* __restrict__ b0, const float* __restrict__ b1, const float* __restrict__ b2,
    unsigned short* __restrict__ outb, float* __restrict__ outf, float scale0) {
  const int p = blockIdx.z;
  const float* Af = (p == 0) ? af0 : (p == 1 ? af1 : af2);
  const unsigned short* W = Wbase + (size_t)p * F_ * F_;
  const float* bias = (p == 0) ? b0 : (p == 1 ? b1 : b2);
  const float sc = (p == 0) ? scale0 : 1.0f;

  const int tid = threadIdx.x;
  const int wid = tid >> 6, lane = tid & 63;
  const int lr = lane & 15, lg = lane >> 4;
  const int wr = wid >> 1, wc = wid & 1;
  const int m0 = blockIdx.x * 128, n0 = blockIdx.y * 128;

  __shared__ __align__(16) unsigned short As[128 * 32];
  __shared__ __align__(16) unsigned short Bs[128 * 32];

  f32x4 acc[4][4] = {};

  for (int k0 = 0; k0 < F_; k0 += 32) {
#pragma unroll
    for (int i = 0; i < 2; ++i) {
      const int ch = i * 256 + tid;
      const int r = ch >> 2, s = ch & 3;
      if constexpr (A_F32) {
        const float* src = Af + (size_t)(m0 + r) * F_ + k0 + s * 8;
        float4 x0 = *(const float4*)src;
        float4 x1 = *(const float4*)(src + 4);
        union { unsigned w[4]; bf16x8 v; } t;
        t.w[0] = cvtpk(x0.x, x0.y); t.w[1] = cvtpk(x0.z, x0.w);
        t.w[2] = cvtpk(x1.x, x1.y); t.w[3] = cvtpk(x1.z, x1.w);
        *(bf16x8*)&As[ch * 8] = t.v;
      } else {
        gload_lds16(Abf + (size_t)(m0 + r) * F_ + k0 + s * 8, &As[(i * 256 + wid * 64) * 8]);
      }
      gload_lds16(W + (size_t)(n0 + r) * F_ + k0 + s * 8, &Bs[(i * 256 + wid * 64) * 8]);
    }
    __syncthreads();

    bf16x8 af[4], bf[4];
#pragma unroll
    for (int m = 0; m < 4; ++m)
      af[m] = *(const bf16x8*)&As[(wr * 64 + m * 16 + lr) * 32 + lg * 8];
#pragma unroll
    for (int n = 0; n < 4; ++n)
      bf[n] = *(const bf16x8*)&Bs[(wc * 64 + n * 16 + lr) * 32 + lg * 8];
#pragma unroll
    for (int m = 0; m < 4; ++m)
#pragma unroll
      for (int n = 0; n < 4; ++n)
        acc[m][n] = __builtin_amdgcn_mfma_f32_16x16x32_bf16(af[m], bf[n], acc[m][n], 0, 0, 0);
    __syncthreads();
  }

  unsigned short* ob = OUT_F32 ? nullptr : outb + (size_t)p * BT_ * F_;
#pragma unroll
  for (int n = 0; n < 4; ++n) {
    const int col = n0 + wc * 64 + n * 16 + lr;
    const float bv = bias[col];
#pragma unroll
    for (int m = 0; m < 4; ++m) {
      const int rbase = m0 + wr * 64 + m * 16 + lg * 4;
#pragma unroll
      for (int j = 0; j < 4; ++j) {
        const float v = (acc[m][n][j] + bv) * sc;
        if constexpr (OUT_F32) outf[(size_t)(rbase + j) * F_ + col] = v;
        else                   ob[(size_t)(rbase + j) * F_ + col] = f2bf(v);
      }
    }
  }
}

// ---------------- V transpose: (B,T,F)-per-head -> [BH][DK][T] ----------------
__global__ void transpose_v(const unsigned short* __restrict__ Vp, unsigned short* __restrict__ Vt) {
  const int bh = blockIdx.y, b = bh >> 3, h = bh & 7;
  const int t0 = blockIdx.x * 64;
  const int tid = threadIdx.x;
  __shared__ __align__(16) unsigned short tile[64][72];

#pragma unroll
  for (int i = 0; i < 2; ++i) {
    const int ch = i * 256 + tid;          // 512 chunks of 8
    const int t = ch >> 3, s = ch & 7;
    bf16x8 v = *(const bf16x8*)(Vp + (size_t)(b * T_ + t0 + t) * F_ + h * DK_ + s * 8);
    *(bf16x8*)&tile[t][s * 8] = v;
  }
  __syncthreads();
#pragma unroll
  for (int i = 0; i < 2; ++i) {
    const int ch = i * 256 + tid;
    const int d = ch >> 3, s = ch & 7;
    union { unsigned short u[8]; bf16x8 v; } r;
#pragma unroll
    for (int j = 0; j < 8; ++j) r.u[j] = tile[s * 8 + j][d];
    *(bf16x8*)(Vt + ((size_t)bh * DK_ + d) * T_ + t0 + s * 8) = r.v;
  }
}

// ---------------- flash attention, swapped-operand 32x32, XCD-swizzled ----------------
// 4 waves x 32 q-rows = 128 q/block; KV tile 64, double-buffered K/V^T/mask in LDS.
// S^T = mfma(K, Q): lane owns ONE q-row; softmax in-register (cvt_pk + permlane32_swap
// for the P half-exchange). O^T = mfma(V^T, P^T). Q pre-scaled by 0.125*log2e.
// Grid is 1D 512; bijective XCD swizzle groups each head's 16 q-blocks onto one XCD
// so its K/V working set (4 heads x 512 KB = 2 MB) stays L2-resident.
__global__ __launch_bounds__(256, 2) void attn_kernel(
    const unsigned short* __restrict__ Qp,
    const unsigned short* __restrict__ Kp,
    const unsigned short* __restrict__ Vt,
    const float* __restrict__ maskf,
    unsigned short* __restrict__ X) {
  const int tid = threadIdx.x, wid = tid >> 6, lane = tid & 63;
  const int la = lane & 31, hi = lane >> 5;
  // XCD-aware swizzle: hardware round-robins linear block id across 8 XCDs.
  // id%8 == c -> XCD c; give XCD c the c-th chunk of 64 (bh,qb) slots.
  const int id = blockIdx.x;                  // 0..511
  const int swz = (id & 7) * 64 + (id >> 3);  // bijective
  const int bh = swz >> 4, qb = swz & 15;
  const int b = bh >> 3, h = bh & 7;
  const int qrow = qb * 128 + wid * 32 + la;

  __shared__ __align__(16) unsigned short Ks[2][64 * 64];  // [kv][dk], 16B-slot XOR swizzle
  __shared__ __align__(16) unsigned short Vs[2][64 * 64];  // [d][kv], swizzled
  __shared__ __align__(16) float Ms[2][64];                // mask addend

  // Q B-fragments (held for whole block): B[k=kk*16+hi*8+e][col=la]
  bf16x8 qf[4];
#pragma unroll
  for (int kk = 0; kk < 4; ++kk)
    qf[kk] = *(const bf16x8*)(Qp + (size_t)(b * T_ + qrow) * F_ + h * DK_ + kk * 16 + hi * 8);

  f32x16 oacc[2] = {};
  float mrun = -1e30f, lrun = 0.0f;

  auto stage = [&](int buf, int kv0) {
#pragma unroll
    for (int i = 0; i < 2; ++i) {
      const int ch = i * 256 + tid;
      const int r = ch >> 3, s = ch & 7;
      gload_lds16(Kp + (size_t)(b * T_ + kv0 + r) * F_ + h * DK_ + ((s ^ (r & 7)) * 8),
                  &Ks[buf][(i * 256 + wid * 64) * 8]);
      gload_lds16(Vt + ((size_t)bh * DK_ + r) * T_ + kv0 + ((s ^ (r & 7)) * 8),
                  &Vs[buf][(i * 256 + wid * 64) * 8]);
    }
    if (wid == 0 && lane < 16)
      gload_lds16(maskf + b * T_ + kv0 + lane * 4, &Ms[buf][0]);
  };

  stage(0, 0);
  __syncthreads();

  for (int t = 0; t < 32; ++t) {
    const int cur = t & 1;
    if (t < 31) stage(cur ^ 1, (t + 1) * 64);

    // K A-fragments: A[row=kv=n*32+la][k=kk*16+hi*8+e]
    bf16x8 kf0[4], kf1[4];
#pragma unroll
    for (int kk = 0; kk < 4; ++kk) {
      kf0[kk] = *(const bf16x8*)&Ks[cur][la * 64 + (((2 * kk + hi) ^ (la & 7)) * 8)];
      kf1[kk] = *(const bf16x8*)&Ks[cur][(32 + la) * 64 + (((2 * kk + hi) ^ (la & 7)) * 8)];
    }
    // mask addend, broadcast reads
    f32x4 mfv[2][4];
#pragma unroll
    for (int n = 0; n < 2; ++n)
#pragma unroll
      for (int g = 0; g < 4; ++g)
        mfv[n][g] = *(const f32x4*)&Ms[cur][n * 32 + 8 * g + 4 * hi];

    // S^T = K · Q^T  (col = q-row = la, row = kv)
    f32x16 s0 = {}, s1 = {};
    __builtin_amdgcn_s_setprio(1);
#pragma unroll
    for (int kk = 0; kk < 4; ++kk) {
      s0 = __builtin_amdgcn_mfma_f32_32x32x16_bf16(kf0[kk], qf[kk], s0, 0, 0, 0);
      s1 = __builtin_amdgcn_mfma_f32_32x32x16_bf16(kf1[kk], qf[kk], s1, 0, 0, 0);
    }
    __builtin_amdgcn_s_setprio(0);

    // row max (raw/unmasked is a valid overestimate)
    float mx[16];
#pragma unroll
    for (int r = 0; r < 16; ++r) mx[r] = fmaxf(s0[r], s1[r]);
#pragma unroll
    for (int st = 8; st > 0; st >>= 1)
#pragma unroll
      for (int r = 0; r < st; ++r) mx[r] = fmaxf(mx[r], mx[r + st]);
    const float rmx = fmaxf(mx[0], __shfl_xor(mx[0], 32, 64));

    // defer-max (T13): rescale only when max grew beyond THR=8 (exp2 domain)
    if (!__all(rmx <= mrun + 8.0f)) {
      const float mnew = fmaxf(mrun, rmx);
      const float alpha = __builtin_amdgcn_exp2f(mrun - mnew);
      lrun *= alpha;
#pragma unroll
      for (int m = 0; m < 2; ++m)
#pragma unroll
        for (int r = 0; r < 16; ++r) oacc[m][r] *= alpha;
      mrun = mnew;
    }

    // P = exp2(S + mask - m)
    float p0[16], p1[16];
#pragma unroll
    for (int r = 0; r < 16; ++r) {
      p0[r] = __builtin_amdgcn_exp2f((s0[r] + mfv[0][r >> 2][r & 3]) - mrun);
      p1[r] = __builtin_amdgcn_exp2f((s1[r] + mfv[1][r >> 2][r & 3]) - mrun);
    }
    float sm[16];
#pragma unroll
    for (int r = 0; r < 16; ++r) sm[r] = p0[r] + p1[r];
#pragma unroll
    for (int st = 8; st > 0; st >>= 1)
#pragma unroll
      for (int r = 0; r < st; ++r) sm[r] += sm[r + st];
    lrun += sm[0] + __shfl_xor(sm[0], 32, 64);

    // pack P pairs to bf16 words; exchange halves via permlane32_swap:
    // after swap(xE, xO): xE = low-words (w0,w1), xO = high-words (w2,w3)
    unsigned lowr[2][2][2], uppr[2][2][2];
#pragma unroll
    for (int n = 0; n < 2; ++n)
#pragma unroll
      for (int gg = 0; gg < 2; ++gg)
#pragma unroll
        for (int hh = 0; hh < 2; ++hh) {
          const float* ps = (n == 0) ? p0 : p1;
          unsigned xE = cvtpk(ps[4 * (2 * gg) + 2 * hh], ps[4 * (2 * gg) + 2 * hh + 1]);
          unsigned xO = cvtpk(ps[4 * (2 * gg + 1) + 2 * hh], ps[4 * (2 * gg + 1) + 2 * hh + 1]);
          asm("v_permlane32_swap_b32 %0, %1" : "+v"(xE), "+v"(xO));
          lowr[n][gg][hh] = xE;
          uppr[n][gg][hh] = xO;
        }

    // O^T += V^T · P^T
#pragma unroll
    for (int kt = 0; kt < 4; ++kt) {
      const int n = kt >> 1, gg = kt & 1;
      union { unsigned w[4]; bf16x8 v; } pf;
      pf.w[0] = lowr[n][gg][0]; pf.w[1] = lowr[n][gg][1];
      pf.w[2] = uppr[n][gg][0]; pf.w[3] = uppr[n][gg][1];
      __builtin_amdgcn_s_setprio(1);
#pragma unroll
      for (int m = 0; m < 2; ++m) {
        bf16x8 vfr = *(const bf16x8*)&Vs[cur][(m * 32 + la) * 64 + (((2 * kt + hi) ^ (la & 7)) * 8)];
        oacc[m] = __builtin_amdgcn_mfma_f32_32x32x16_bf16(vfr, pf.v, oacc[m], 0, 0, 0);
      }
      __builtin_amdgcn_s_setprio(0);
    }
    __syncthreads();   // drains vmcnt: next tile staged; buf[cur] reads all done
  }

  // normalize + write X: thread owns q-row, d = m*32 + 8g + 4hi + j
  const float inv = 1.0f / fmaxf(lrun, 1e-37f);
#pragma unroll
  for (int m = 0; m < 2; ++m)
#pragma unroll
    for (int g = 0; g < 4; ++g) {
      union { unsigned short u[4]; s16x4 v; } ov;
#pragma unroll
      for (int j = 0; j < 4; ++j) ov.u[j] = f2bf(oacc[m][4 * g + j] * inv);
      *(s16x4*)(X + (size_t)(b * T_ + qrow) * F_ + h * DK_ + m * 32 + 8 * g + 4 * hi) = ov.v;
    }
}

// ---------------- launcher ----------------
extern "C" void kernel_launch(void* const* d_in, const int* in_sizes, int n_in,
                              void* d_out, int out_size, void* d_ws, size_t ws_size,
                              hipStream_t stream) {
  const float* q  = (const float*)d_in[0];
  const float* k  = (const float*)d_in[1];
  const float* v  = (const float*)d_in[2];
  const int* mask = (const int*)d_in[3];
  const float* Wq = (const float*)d_in[4];
  const float* bq = (const float*)d_in[5];
  const float* Wk = (const float*)d_in[6];
  const float* bk = (const float*)d_in[7];
  const float* Wv = (const float*)d_in[8];
  const float* bv = (const float*)d_in[9];
  const float* Wo = (const float*)d_in[10];
  const float* bo = (const float*)d_in[11];
  float* out = (float*)d_out;

  unsigned short* ws = (unsigned short*)d_ws;
  unsigned short* wts  = ws;                               // 4*F*F = 1,048,576 us
  unsigned short* proj = wts + (size_t)4 * F_ * F_;        // 3*BT*F
  unsigned short* vt   = proj + (size_t)3 * BT_ * F_;      // BT*F
  unsigned short* xbuf = vt + (size_t)BT_ * F_;            // BT*F
  float* maskf = (float*)(xbuf + (size_t)BT_ * F_);        // B*T f32 + slack

  const float kQScale = 0.18033688011112042f;  // (1/sqrt(64)) * log2(e)

  convert_w<<<dim3(128, 5, 1), 256, 0, stream>>>(Wq, Wk, Wv, Wo, mask, wts, maskf);
  gemm_bt<true, false><<<dim3(64, 4, 3), 256, 0, stream>>>(
      q, k, v, nullptr, wts, bq, bk, bv, proj, nullptr, kQScale);
  transpose_v<<<dim3(32, 32, 1), 256, 0, stream>>>(proj + (size_t)2 * BT_ * F_, vt);
  attn_kernel<<<dim3(512, 1, 1), 256, 0, stream>>>(
      proj, proj + (size_t)BT_ * F_, vt, maskf, xbuf);
  gemm_bt<false, true><<<dim3(64, 4, 1), 256, 0, stream>>>(
      nullptr, nullptr, nullptr, xbuf, wts + (size_t)3 * F_ * F_, bo, bo, bo, nullptr, out, 1.0f);
}

// Round 7
// 103.071 us; speedup vs baseline: 1.8700x; 1.0962x over previous
//
#include <hip/hip_runtime.h>
#include <hip/hip_bf16.h>
#include <stdint.h>

#define B_ 4
#define T_ 2048
#define F_ 512
#define H_ 8
#define DK_ 64
#define BT_ (B_*T_)   // 8192

typedef short bf16x8 __attribute__((ext_vector_type(8)));
typedef short s16x4 __attribute__((ext_vector_type(4)));
typedef float f32x4 __attribute__((ext_vector_type(4)));
typedef float f32x16 __attribute__((ext_vector_type(16)));

__device__ __forceinline__ unsigned short f2bf(float f) {
  union { float f; unsigned u; } v; v.f = f;
  return (unsigned short)((v.u + 0x7fffu + ((v.u >> 16) & 1u)) >> 16);
}

__device__ __forceinline__ unsigned cvtpk(float lo, float hi) {
  unsigned w;
  asm("v_cvt_pk_bf16_f32 %0, %1, %2" : "=v"(w) : "v"(lo), "v"(hi));
  return w;
}

__device__ __forceinline__ void gload_lds16(const void* g, void* l) {
  __builtin_amdgcn_global_load_lds((const __attribute__((address_space(1))) void*)g,
                                   (__attribute__((address_space(3))) void*)l, 16, 0, 0);
}

// ---------------- weight conversion fp32 -> bf16 ----------------
__global__ void convert_w(const float* __restrict__ wq, const float* __restrict__ wk,
                          const float* __restrict__ wv, const float* __restrict__ wo,
                          unsigned short* __restrict__ dst) {
  const int seg = blockIdx.y;
  const float* src = seg == 0 ? wq : (seg == 1 ? wk : (seg == 2 ? wv : wo));
  unsigned short* out = dst + (size_t)seg * F_ * F_;
  const int idx = (blockIdx.x * 256 + threadIdx.x) * 8;   // 128 blocks * 256 * 8 = 262144 exact
  float4 a = *(const float4*)(src + idx);
  float4 b = *(const float4*)(src + idx + 4);
  union { unsigned w[4]; bf16x8 v; } t;
  t.w[0] = cvtpk(a.x, a.y); t.w[1] = cvtpk(a.z, a.w);
  t.w[2] = cvtpk(b.x, b.y); t.w[3] = cvtpk(b.z, b.w);
  *(bf16x8*)(out + idx) = t.v;
}

// ---------------- mask scan: per-batch prefix sum -> invidx, nb ----------------
__global__ void scan_mask(const int* __restrict__ mask, int* __restrict__ invidx,
                          int* __restrict__ nbuf) {
  const int b = blockIdx.x, tid = threadIdx.x;
  __shared__ int cnt[256];
  const int base = b * T_ + tid * 8;
  int4 a = *(const int4*)(mask + base);
  int4 d = *(const int4*)(mask + base + 4);
  int m[8] = {a.x, a.y, a.z, a.w, d.x, d.y, d.z, d.w};
  int c = 0;
#pragma unroll
  for (int i = 0; i < 8; ++i) c += (m[i] != 0);
  cnt[tid] = c;
  __syncthreads();
  for (int off = 1; off < 256; off <<= 1) {
    int v = (tid >= off) ? cnt[tid - off] : 0;
    __syncthreads();
    cnt[tid] += v;
    __syncthreads();
  }
  int excl = cnt[tid] - c;
#pragma unroll
  for (int i = 0; i < 8; ++i)
    if (m[i]) { invidx[b * T_ + excl] = tid * 8 + i; ++excl; }
  if (tid == 255) nbuf[b] = cnt[255];
}

// ---------------- gather K rows (compacted) + zero pad + compacted mask addend ----------------
__global__ void gather_k(const unsigned short* __restrict__ Kproj,
                         const int* __restrict__ invidx, const int* __restrict__ nbuf,
                         unsigned short* __restrict__ Kc, float* __restrict__ maskf) {
  const int b = blockIdx.y, j0 = blockIdx.x * 64, tid = threadIdx.x;
  const int nb = nbuf[b];
  const int ce = (nb + 63) & ~63;
  if (tid < 64) maskf[b * T_ + j0 + tid] = (j0 + tid < nb) ? 0.0f : -__builtin_inff();
  if (j0 >= ce) return;
#pragma unroll
  for (int i = 0; i < 16; ++i) {
    const int ch = i * 256 + tid;          // 4096 chunks: row = ch>>6, slice = ch&63
    const int j = j0 + (ch >> 6), s = ch & 63;
    if (j < nb) {
      const int src = invidx[b * T_ + j];
      *(bf16x8*)(Kc + (size_t)(b * T_ + j) * F_ + s * 8) =
          *(const bf16x8*)(Kproj + (size_t)(b * T_ + src) * F_ + s * 8);
    } else if (j < ce) {
      bf16x8 z = {};
      *(bf16x8*)(Kc + (size_t)(b * T_ + j) * F_ + s * 8) = z;
    }
  }
}

// ---------------- GEMM: C = (A @ W^T + bias) * sc ----------------
template <bool A_F32, bool OUT_F32>
__global__ __launch_bounds__(256, 2) void gemm_bt(
    const float* __restrict__ af0, const float* __restrict__ af1, const float* __restrict__ af2,
    const unsigned short* __restrict__ Abf,
    const unsigned short* __restrict__ Wbase,
    const float* __restrict__ b0, const float* __restrict__ b1, const float* __restrict__ b2,
    unsigned short* __restrict__ outb, float* __restrict__ outf, float scale0) {
  const int p = blockIdx.z;
  const float* Af = (p == 0) ? af0 : (p == 1 ? af1 : af2);
  const unsigned short* W = Wbase + (size_t)p * F_ * F_;
  const float* bias = (p == 0) ? b0 : (p == 1 ? b1 : b2);
  const float sc = (p == 0) ? scale0 : 1.0f;

  const int tid = threadIdx.x;
  const int wid = tid >> 6, lane = tid & 63;
  const int lr = lane & 15, lg = lane >> 4;
  const int wr = wid >> 1, wc = wid & 1;
  const int m0 = blockIdx.x * 128, n0 = blockIdx.y * 128;

  __shared__ __align__(16) unsigned short As[128 * 32];
  __shared__ __align__(16) unsigned short Bs[128 * 32];

  f32x4 acc[4][4] = {};

  for (int k0 = 0; k0 < F_; k0 += 32) {
#pragma unroll
    for (int i = 0; i < 2; ++i) {
      const int ch = i * 256 + tid;
      const int r = ch >> 2, s = ch & 3;
      if constexpr (A_F32) {
        const float* src = Af + (size_t)(m0 + r) * F_ + k0 + s * 8;
        float4 x0 = *(const float4*)src;
        float4 x1 = *(const float4*)(src + 4);
        union { unsigned w[4]; bf16x8 v; } t;
        t.w[0] = cvtpk(x0.x, x0.y); t.w[1] = cvtpk(x0.z, x0.w);
        t.w[2] = cvtpk(x1.x, x1.y); t.w[3] = cvtpk(x1.z, x1.w);
        *(bf16x8*)&As[ch * 8] = t.v;
      } else {
        gload_lds16(Abf + (size_t)(m0 + r) * F_ + k0 + s * 8, &As[(i * 256 + wid * 64) * 8]);
      }
      gload_lds16(W + (size_t)(n0 + r) * F_ + k0 + s * 8, &Bs[(i * 256 + wid * 64) * 8]);
    }
    __syncthreads();

    bf16x8 af[4], bf[4];
#pragma unroll
    for (int m = 0; m < 4; ++m)
      af[m] = *(const bf16x8*)&As[(wr * 64 + m * 16 + lr) * 32 + lg * 8];
#pragma unroll
    for (int n = 0; n < 4; ++n)
      bf[n] = *(const bf16x8*)&Bs[(wc * 64 + n * 16 + lr) * 32 + lg * 8];
#pragma unroll
    for (int m = 0; m < 4; ++m)
#pragma unroll
      for (int n = 0; n < 4; ++n)
        acc[m][n] = __builtin_amdgcn_mfma_f32_16x16x32_bf16(af[m], bf[n], acc[m][n], 0, 0, 0);
    __syncthreads();
  }

  unsigned short* ob = OUT_F32 ? nullptr : outb + (size_t)p * BT_ * F_;
#pragma unroll
  for (int n = 0; n < 4; ++n) {
    const int col = n0 + wc * 64 + n * 16 + lr;
    const float bv = bias[col];
#pragma unroll
    for (int m = 0; m < 4; ++m) {
      const int rbase = m0 + wr * 64 + m * 16 + lg * 4;
#pragma unroll
      for (int j = 0; j < 4; ++j) {
        const float v = (acc[m][n][j] + bv) * sc;
        if constexpr (OUT_F32) outf[(size_t)(rbase + j) * F_ + col] = v;
        else                   ob[(size_t)(rbase + j) * F_ + col] = f2bf(v);
      }
    }
  }
}

// ---------------- gather-transpose V: compacted (B,T,F)-per-head -> [BH][DK][Tc] ----------------
__global__ void transpose_v(const unsigned short* __restrict__ Vp,
                            const int* __restrict__ invidx, const int* __restrict__ nbuf,
                            unsigned short* __restrict__ Vt) {
  const int bh = blockIdx.y, b = bh >> 3, h = bh & 7;
  const int t0 = blockIdx.x * 64;
  const int tid = threadIdx.x;
  const int nb = nbuf[b];
  const int ce = (nb + 63) & ~63;
  if (t0 >= ce) return;
  __shared__ __align__(16) unsigned short tile[64][72];

#pragma unroll
  for (int i = 0; i < 2; ++i) {
    const int ch = i * 256 + tid;          // 512 chunks of 8
    const int t = ch >> 3, s = ch & 7;
    bf16x8 v = {};
    if (t0 + t < nb) {
      const int src = invidx[b * T_ + t0 + t];
      v = *(const bf16x8*)(Vp + (size_t)(b * T_ + src) * F_ + h * DK_ + s * 8);
    }
    *(bf16x8*)&tile[t][s * 8] = v;
  }
  __syncthreads();
#pragma unroll
  for (int i = 0; i < 2; ++i) {
    const int ch = i * 256 + tid;
    const int d = ch >> 3, s = ch & 7;
    union { unsigned short u[8]; bf16x8 v; } r;
#pragma unroll
    for (int j = 0; j < 8; ++j) r.u[j] = tile[s * 8 + j][d];
    *(bf16x8*)(Vt + ((size_t)bh * DK_ + d) * T_ + t0 + s * 8) = r.v;
  }
}

// ---------------- flash attention, swapped-operand 32x32, XCD-swizzled, compacted kv ----------------
// 4 waves x 32 q-rows = 128 q/block; KV tile 64 over the COMPACTED kv range (nt tiles),
// double-buffered K/V^T/mask in LDS. S^T = mfma(K, Q): lane owns ONE q-row; softmax
// in-register (cvt_pk + permlane32_swap). O^T = mfma(V^T, P^T). Q pre-scaled 0.125*log2e.
__global__ __launch_bounds__(256, 2) void attn_kernel(
    const unsigned short* __restrict__ Qp,
    const unsigned short* __restrict__ Kp,
    const unsigned short* __restrict__ Vt,
    const float* __restrict__ maskf,
    const int* __restrict__ nbuf,
    unsigned short* __restrict__ X) {
  const int tid = threadIdx.x, wid = tid >> 6, lane = tid & 63;
  const int la = lane & 31, hi = lane >> 5;
  // XCD-aware bijective swizzle: id%8 -> XCD; give each XCD a contiguous (bh,qb) chunk.
  const int id = blockIdx.x;                  // 0..511
  const int swz = (id & 7) * 64 + (id >> 3);
  const int bh = swz >> 4, qb = swz & 15;
  const int b = bh >> 3, h = bh & 7;
  const int qrow = qb * 128 + wid * 32 + la;
  const int nt = (nbuf[b] + 63) >> 6;         // compacted tile count

  __shared__ __align__(16) unsigned short Ks[2][64 * 64];  // [kv][dk], 16B-slot XOR swizzle
  __shared__ __align__(16) unsigned short Vs[2][64 * 64];  // [d][kv], swizzled
  __shared__ __align__(16) float Ms[2][64];                // mask addend (tail -inf)

  // Q B-fragments (held for whole block): B[k=kk*16+hi*8+e][col=la]
  bf16x8 qf[4];
#pragma unroll
  for (int kk = 0; kk < 4; ++kk)
    qf[kk] = *(const bf16x8*)(Qp + (size_t)(b * T_ + qrow) * F_ + h * DK_ + kk * 16 + hi * 8);

  f32x16 oacc[2] = {};
  float mrun = -1e30f, lrun = 0.0f;

  auto stage = [&](int buf, int kv0) {
#pragma unroll
    for (int i = 0; i < 2; ++i) {
      const int ch = i * 256 + tid;
      const int r = ch >> 3, s = ch & 7;
      gload_lds16(Kp + (size_t)(b * T_ + kv0 + r) * F_ + h * DK_ + ((s ^ (r & 7)) * 8),
                  &Ks[buf][(i * 256 + wid * 64) * 8]);
      gload_lds16(Vt + ((size_t)bh * DK_ + r) * T_ + kv0 + ((s ^ (r & 7)) * 8),
                  &Vs[buf][(i * 256 + wid * 64) * 8]);
    }
    if (wid == 0 && lane < 16)
      gload_lds16(maskf + b * T_ + kv0 + lane * 4, &Ms[buf][0]);
  };

  if (nt > 0) {
    stage(0, 0);
    __syncthreads();

    for (int t = 0; t < nt; ++t) {
      const int cur = t & 1;
      if (t < nt - 1) stage(cur ^ 1, (t + 1) * 64);

      // K A-fragments: A[row=kv=n*32+la][k=kk*16+hi*8+e]
      bf16x8 kf0[4], kf1[4];
#pragma unroll
      for (int kk = 0; kk < 4; ++kk) {
        kf0[kk] = *(const bf16x8*)&Ks[cur][la * 64 + (((2 * kk + hi) ^ (la & 7)) * 8)];
        kf1[kk] = *(const bf16x8*)&Ks[cur][(32 + la) * 64 + (((2 * kk + hi) ^ (la & 7)) * 8)];
      }
      // mask addend, broadcast reads
      f32x4 mfv[2][4];
#pragma unroll
      for (int n = 0; n < 2; ++n)
#pragma unroll
        for (int g = 0; g < 4; ++g)
          mfv[n][g] = *(const f32x4*)&Ms[cur][n * 32 + 8 * g + 4 * hi];

      // S^T = K · Q^T  (col = q-row = la, row = kv)
      f32x16 s0 = {}, s1 = {};
      __builtin_amdgcn_s_setprio(1);
#pragma unroll
      for (int kk = 0; kk < 4; ++kk) {
        s0 = __builtin_amdgcn_mfma_f32_32x32x16_bf16(kf0[kk], qf[kk], s0, 0, 0, 0);
        s1 = __builtin_amdgcn_mfma_f32_32x32x16_bf16(kf1[kk], qf[kk], s1, 0, 0, 0);
      }
      __builtin_amdgcn_s_setprio(0);

      // row max (raw/unmasked is a valid overestimate; pad rows give s=0)
      float mx[16];
#pragma unroll
      for (int r = 0; r < 16; ++r) mx[r] = fmaxf(s0[r], s1[r]);
#pragma unroll
      for (int st = 8; st > 0; st >>= 1)
#pragma unroll
        for (int r = 0; r < st; ++r) mx[r] = fmaxf(mx[r], mx[r + st]);
      const float rmx = fmaxf(mx[0], __shfl_xor(mx[0], 32, 64));

      // defer-max (T13): rescale only when max grew beyond THR=8 (exp2 domain)
      if (!__all(rmx <= mrun + 8.0f)) {
        const float mnew = fmaxf(mrun, rmx);
        const float alpha = __builtin_amdgcn_exp2f(mrun - mnew);
        lrun *= alpha;
#pragma unroll
        for (int m = 0; m < 2; ++m)
#pragma unroll
          for (int r = 0; r < 16; ++r) oacc[m][r] *= alpha;
        mrun = mnew;
      }

      // P = exp2(S + mask - m)
      float p0[16], p1[16];
#pragma unroll
      for (int r = 0; r < 16; ++r) {
        p0[r] = __builtin_amdgcn_exp2f((s0[r] + mfv[0][r >> 2][r & 3]) - mrun);
        p1[r] = __builtin_amdgcn_exp2f((s1[r] + mfv[1][r >> 2][r & 3]) - mrun);
      }
      float sm[16];
#pragma unroll
      for (int r = 0; r < 16; ++r) sm[r] = p0[r] + p1[r];
#pragma unroll
      for (int st = 8; st > 0; st >>= 1)
#pragma unroll
        for (int r = 0; r < st; ++r) sm[r] += sm[r + st];
      lrun += sm[0] + __shfl_xor(sm[0], 32, 64);

      // pack P pairs to bf16 words; exchange halves via permlane32_swap
      unsigned lowr[2][2][2], uppr[2][2][2];
#pragma unroll
      for (int n = 0; n < 2; ++n)
#pragma unroll
        for (int gg = 0; gg < 2; ++gg)
#pragma unroll
          for (int hh = 0; hh < 2; ++hh) {
            const float* ps = (n == 0) ? p0 : p1;
            unsigned xE = cvtpk(ps[4 * (2 * gg) + 2 * hh], ps[4 * (2 * gg) + 2 * hh + 1]);
            unsigned xO = cvtpk(ps[4 * (2 * gg + 1) + 2 * hh], ps[4 * (2 * gg + 1) + 2 * hh + 1]);
            asm("v_permlane32_swap_b32 %0, %1" : "+v"(xE), "+v"(xO));
            lowr[n][gg][hh] = xE;
            uppr[n][gg][hh] = xO;
          }

      // O^T += V^T · P^T
#pragma unroll
      for (int kt = 0; kt < 4; ++kt) {
        const int n = kt >> 1, gg = kt & 1;
        union { unsigned w[4]; bf16x8 v; } pf;
        pf.w[0] = lowr[n][gg][0]; pf.w[1] = lowr[n][gg][1];
        pf.w[2] = uppr[n][gg][0]; pf.w[3] = uppr[n][gg][1];
        __builtin_amdgcn_s_setprio(1);
#pragma unroll
        for (int m = 0; m < 2; ++m) {
          bf16x8 vfr = *(const bf16x8*)&Vs[cur][(m * 32 + la) * 64 + (((2 * kt + hi) ^ (la & 7)) * 8)];
          oacc[m] = __builtin_amdgcn_mfma_f32_32x32x16_bf16(vfr, pf.v, oacc[m], 0, 0, 0);
        }
        __builtin_amdgcn_s_setprio(0);
      }
      __syncthreads();   // drains vmcnt: next tile staged; buf[cur] reads all done
    }
  }

  // normalize + write X: thread owns q-row, d = m*32 + 8g + 4hi + j
  const float inv = 1.0f / fmaxf(lrun, 1e-37f);
#pragma unroll
  for (int m = 0; m < 2; ++m)
#pragma unroll
    for (int g = 0; g < 4; ++g) {
      union { unsigned short u[4]; s16x4 v; } ov;
#pragma unroll
      for (int j = 0; j < 4; ++j) ov.u[j] = f2bf(oacc[m][4 * g + j] * inv);
      *(s16x4*)(X + (size_t)(b * T_ + qrow) * F_ + h * DK_ + m * 32 + 8 * g + 4 * hi) = ov.v;
    }
}

// ---------------- launcher ----------------
extern "C" void kernel_launch(void* const* d_in, const int* in_sizes, int n_in,
                              void* d_out, int out_size, void* d_ws, size_t ws_size,
                              hipStream_t stream) {
  const float* q  = (const float*)d_in[0];
  const float* k  = (const float*)d_in[1];
  const float* v  = (const float*)d_in[2];
  const int* mask = (const int*)d_in[3];
  const float* Wq = (const float*)d_in[4];
  const float* bq = (const float*)d_in[5];
  const float* Wk = (const float*)d_in[6];
  const float* bk = (const float*)d_in[7];
  const float* Wv = (const float*)d_in[8];
  const float* bv = (const float*)d_in[9];
  const float* Wo = (const float*)d_in[10];
  const float* bo = (const float*)d_in[11];
  float* out = (float*)d_out;

  unsigned short* ws = (unsigned short*)d_ws;
  unsigned short* wts  = ws;                               // 4*F*F = 1,048,576 us
  unsigned short* proj = wts + (size_t)4 * F_ * F_;        // 3*BT*F (Q,K,V)
  unsigned short* vt   = proj + (size_t)3 * BT_ * F_;      // BT*F
  unsigned short* xbuf = vt + (size_t)BT_ * F_;            // BT*F
  unsigned short* kc   = xbuf + (size_t)BT_ * F_;          // BT*F (compacted K)
  float* maskf = (float*)(kc + (size_t)BT_ * F_);          // B*T f32
  int* invidx  = (int*)(maskf + BT_);                      // B*T int
  int* nbuf    = invidx + BT_;                             // B int

  const float kQScale = 0.18033688011112042f;  // (1/sqrt(64)) * log2(e)

  convert_w<<<dim3(128, 4, 1), 256, 0, stream>>>(Wq, Wk, Wv, Wo, wts);
  scan_mask<<<dim3(B_, 1, 1), 256, 0, stream>>>(mask, invidx, nbuf);
  gemm_bt<true, false><<<dim3(64, 4, 3), 256, 0, stream>>>(
      q, k, v, nullptr, wts, bq, bk, bv, proj, nullptr, kQScale);
  gather_k<<<dim3(32, B_, 1), 256, 0, stream>>>(
      proj + (size_t)BT_ * F_, invidx, nbuf, kc, maskf);
  transpose_v<<<dim3(32, 32, 1), 256, 0, stream>>>(
      proj + (size_t)2 * BT_ * F_, invidx, nbuf, vt);
  attn_kernel<<<dim3(512, 1, 1), 256, 0, stream>>>(
      proj, kc, vt, maskf, nbuf, xbuf);
  gemm_bt<false, true><<<dim3(64, 4, 1), 256, 0, stream>>>(
      nullptr, nullptr, nullptr, xbuf, wts + (size_t)3 * F_ * F_, bo, bo, bo, nullptr, out, 1.0f);
}

// Round 8
// 102.035 us; speedup vs baseline: 1.8890x; 1.0102x over previous
//
#include <hip/hip_runtime.h>
#include <hip/hip_bf16.h>
#include <stdint.h>

#define B_ 4
#define T_ 2048
#define F_ 512
#define H_ 8
#define DK_ 64
#define BT_ (B_*T_)   // 8192

typedef short bf16x8 __attribute__((ext_vector_type(8)));
typedef short s16x4 __attribute__((ext_vector_type(4)));
typedef float f32x4 __attribute__((ext_vector_type(4)));
typedef float f32x16 __attribute__((ext_vector_type(16)));

__device__ __forceinline__ unsigned short f2bf(float f) {
  union { float f; unsigned u; } v; v.f = f;
  return (unsigned short)((v.u + 0x7fffu + ((v.u >> 16) & 1u)) >> 16);
}

__device__ __forceinline__ unsigned cvtpk(float lo, float hi) {
  unsigned w;
  asm("v_cvt_pk_bf16_f32 %0, %1, %2" : "=v"(w) : "v"(lo), "v"(hi));
  return w;
}

__device__ __forceinline__ void gload_lds16(const void* g, void* l) {
  __builtin_amdgcn_global_load_lds((const __attribute__((address_space(1))) void*)g,
                                   (__attribute__((address_space(3))) void*)l, 16, 0, 0);
}

// ---------------- weight conversion fp32 -> bf16 ----------------
__global__ void convert_w(const float* __restrict__ wq, const float* __restrict__ wk,
                          const float* __restrict__ wv, const float* __restrict__ wo,
                          unsigned short* __restrict__ dst) {
  const int seg = blockIdx.y;
  const float* src = seg == 0 ? wq : (seg == 1 ? wk : (seg == 2 ? wv : wo));
  unsigned short* out = dst + (size_t)seg * F_ * F_;
  const int idx = (blockIdx.x * 256 + threadIdx.x) * 8;   // 128 blocks * 256 * 8 = 262144 exact
  float4 a = *(const float4*)(src + idx);
  float4 b = *(const float4*)(src + idx + 4);
  union { unsigned w[4]; bf16x8 v; } t;
  t.w[0] = cvtpk(a.x, a.y); t.w[1] = cvtpk(a.z, a.w);
  t.w[2] = cvtpk(b.x, b.y); t.w[3] = cvtpk(b.z, b.w);
  *(bf16x8*)(out + idx) = t.v;
}

// ---------------- mask scan: per-batch prefix sum -> invidx, nb ----------------
__global__ void scan_mask(const int* __restrict__ mask, int* __restrict__ invidx,
                          int* __restrict__ nbuf) {
  const int b = blockIdx.x, tid = threadIdx.x;
  __shared__ int cnt[256];
  const int base = b * T_ + tid * 8;
  int4 a = *(const int4*)(mask + base);
  int4 d = *(const int4*)(mask + base + 4);
  int m[8] = {a.x, a.y, a.z, a.w, d.x, d.y, d.z, d.w};
  int c = 0;
#pragma unroll
  for (int i = 0; i < 8; ++i) c += (m[i] != 0);
  cnt[tid] = c;
  __syncthreads();
  for (int off = 1; off < 256; off <<= 1) {
    int v = (tid >= off) ? cnt[tid - off] : 0;
    __syncthreads();
    cnt[tid] += v;
    __syncthreads();
  }
  int excl = cnt[tid] - c;
#pragma unroll
  for (int i = 0; i < 8; ++i)
    if (m[i]) { invidx[b * T_ + excl] = tid * 8 + i; ++excl; }
  if (tid == 255) nbuf[b] = cnt[255];
}

// ---------------- gather K rows (compacted) + zero pad + compacted mask addend ----------------
__global__ void gather_k(const unsigned short* __restrict__ Kproj,
                         const int* __restrict__ invidx, const int* __restrict__ nbuf,
                         unsigned short* __restrict__ Kc, float* __restrict__ maskf) {
  const int b = blockIdx.y, j0 = blockIdx.x * 64, tid = threadIdx.x;
  const int nb = nbuf[b];
  const int ce = (nb + 63) & ~63;
  if (tid < 64) maskf[b * T_ + j0 + tid] = (j0 + tid < nb) ? 0.0f : -__builtin_inff();
  if (j0 >= ce) return;
#pragma unroll
  for (int i = 0; i < 16; ++i) {
    const int ch = i * 256 + tid;          // 4096 chunks: row = ch>>6, slice = ch&63
    const int j = j0 + (ch >> 6), s = ch & 63;
    if (j < nb) {
      const int src = invidx[b * T_ + j];
      *(bf16x8*)(Kc + (size_t)(b * T_ + j) * F_ + s * 8) =
          *(const bf16x8*)(Kproj + (size_t)(b * T_ + src) * F_ + s * 8);
    } else if (j < ce) {
      bf16x8 z = {};
      *(bf16x8*)(Kc + (size_t)(b * T_ + j) * F_ + s * 8) = z;
    }
  }
}

// ---------------- GEMM: C = (A @ W^T + bias) * sc ----------------
// XCD-locality swizzle: flat grid, xcd=id&7 owns m-tiles [8*xcd, 8*xcd+8); the 4 n-blocks
// of each m-tile are co-resident on one XCD -> A re-reads hit that XCD's L2.
// 2-phase double-buffered staging: issue stage(t+1) before compute(t); one barrier/step.
template <bool A_F32, bool OUT_F32>
__global__ __launch_bounds__(256, 3) void gemm_bt(
    const float* __restrict__ af0, const float* __restrict__ af1, const float* __restrict__ af2,
    const unsigned short* __restrict__ Abf,
    const unsigned short* __restrict__ Wbase,
    const float* __restrict__ b0, const float* __restrict__ b1, const float* __restrict__ b2,
    unsigned short* __restrict__ outb, float* __restrict__ outf, float scale0) {
  const int id = blockIdx.x;
  const int xcd = id & 7, sl = id >> 3;
  const int p = sl >> 5, r = sl & 31;
  const int mt = xcd * 8 + (r >> 2), ntl = r & 3;
  const int m0 = mt * 128, n0 = ntl * 128;

  const float* Af = (p == 0) ? af0 : (p == 1 ? af1 : af2);
  const unsigned short* W = Wbase + (size_t)p * F_ * F_;
  const float* bias = (p == 0) ? b0 : (p == 1 ? b1 : b2);
  const float sc = (p == 0) ? scale0 : 1.0f;

  const int tid = threadIdx.x;
  const int wid = tid >> 6, lane = tid & 63;
  const int lr = lane & 15, lg = lane >> 4;
  const int wr = wid >> 1, wc = wid & 1;
  const int srow = tid >> 2, sslc = tid & 3;   // staging row/slice (per i: row += 64)

  __shared__ __align__(16) unsigned short As[2][128 * 32];
  __shared__ __align__(16) unsigned short Bs[2][128 * 32];

  f32x4 acc[4][4] = {};
  float4 a0, a1, a2, a3;   // A fp32 prefetch regs (2 rows x 8 elems)

  auto loadA = [&](int k0) {
    const float* s0p = Af + (size_t)(m0 + srow) * F_ + k0 + sslc * 8;
    const float* s1p = Af + (size_t)(m0 + 64 + srow) * F_ + k0 + sslc * 8;
    a0 = *(const float4*)s0p; a1 = *(const float4*)(s0p + 4);
    a2 = *(const float4*)s1p; a3 = *(const float4*)(s1p + 4);
  };
  auto writeA = [&](int buf) {
    union { unsigned w[4]; bf16x8 v; } t0, t1;
    t0.w[0] = cvtpk(a0.x, a0.y); t0.w[1] = cvtpk(a0.z, a0.w);
    t0.w[2] = cvtpk(a1.x, a1.y); t0.w[3] = cvtpk(a1.z, a1.w);
    t1.w[0] = cvtpk(a2.x, a2.y); t1.w[1] = cvtpk(a2.z, a2.w);
    t1.w[2] = cvtpk(a3.x, a3.y); t1.w[3] = cvtpk(a3.z, a3.w);
    *(bf16x8*)&As[buf][tid * 8] = t0.v;
    *(bf16x8*)&As[buf][(256 + tid) * 8] = t1.v;
  };
  auto stageAb = [&](int buf, int k0) {
#pragma unroll
    for (int i = 0; i < 2; ++i)
      gload_lds16(Abf + (size_t)(m0 + i * 64 + srow) * F_ + k0 + sslc * 8,
                  &As[buf][(i * 256 + wid * 64) * 8]);
  };
  auto stageB = [&](int buf, int k0) {
#pragma unroll
    for (int i = 0; i < 2; ++i)
      gload_lds16(W + (size_t)(n0 + i * 64 + srow) * F_ + k0 + sslc * 8,
                  &Bs[buf][(i * 256 + wid * 64) * 8]);
  };

  // prologue: stage K-step 0 into buffer 0
  if constexpr (A_F32) { loadA(0); } else { stageAb(0, 0); }
  stageB(0, 0);
  if constexpr (A_F32) writeA(0);
  __syncthreads();

  int cur = 0;
  for (int k0 = 0; k0 < F_; k0 += 32) {
    const int nxt = cur ^ 1;
    const bool more = (k0 + 32 < F_);
    if (more) {
      if constexpr (A_F32) { loadA(k0 + 32); } else { stageAb(nxt, k0 + 32); }
      stageB(nxt, k0 + 32);
    }

    bf16x8 af[4], bf[4];
#pragma unroll
    for (int m = 0; m < 4; ++m)
      af[m] = *(const bf16x8*)&As[cur][(wr * 64 + m * 16 + lr) * 32 + lg * 8];
#pragma unroll
    for (int n = 0; n < 4; ++n)
      bf[n] = *(const bf16x8*)&Bs[cur][(wc * 64 + n * 16 + lr) * 32 + lg * 8];
#pragma unroll
    for (int m = 0; m < 4; ++m)
#pragma unroll
      for (int n = 0; n < 4; ++n)
        acc[m][n] = __builtin_amdgcn_mfma_f32_16x16x32_bf16(af[m], bf[n], acc[m][n], 0, 0, 0);

    if (A_F32 && more) writeA(nxt);
    __syncthreads();
    cur = nxt;
  }

  unsigned short* ob = OUT_F32 ? nullptr : outb + (size_t)p * BT_ * F_;
#pragma unroll
  for (int n = 0; n < 4; ++n) {
    const int col = n0 + wc * 64 + n * 16 + lr;
    const float bv = bias[col];
#pragma unroll
    for (int m = 0; m < 4; ++m) {
      const int rbase = m0 + wr * 64 + m * 16 + lg * 4;
#pragma unroll
      for (int j = 0; j < 4; ++j) {
        const float v = (acc[m][n][j] + bv) * sc;
        if constexpr (OUT_F32) outf[(size_t)(rbase + j) * F_ + col] = v;
        else                   ob[(size_t)(rbase + j) * F_ + col] = f2bf(v);
      }
    }
  }
}

// ---------------- gather-transpose V: compacted (B,T,F)-per-head -> [BH][DK][Tc] ----------------
__global__ void transpose_v(const unsigned short* __restrict__ Vp,
                            const int* __restrict__ invidx, const int* __restrict__ nbuf,
                            unsigned short* __restrict__ Vt) {
  const int bh = blockIdx.y, b = bh >> 3, h = bh & 7;
  const int t0 = blockIdx.x * 64;
  const int tid = threadIdx.x;
  const int nb = nbuf[b];
  const int ce = (nb + 63) & ~63;
  if (t0 >= ce) return;
  __shared__ __align__(16) unsigned short tile[64][72];

#pragma unroll
  for (int i = 0; i < 2; ++i) {
    const int ch = i * 256 + tid;          // 512 chunks of 8
    const int t = ch >> 3, s = ch & 7;
    bf16x8 v = {};
    if (t0 + t < nb) {
      const int src = invidx[b * T_ + t0 + t];
      v = *(const bf16x8*)(Vp + (size_t)(b * T_ + src) * F_ + h * DK_ + s * 8);
    }
    *(bf16x8*)&tile[t][s * 8] = v;
  }
  __syncthreads();
#pragma unroll
  for (int i = 0; i < 2; ++i) {
    const int ch = i * 256 + tid;
    const int d = ch >> 3, s = ch & 7;
    union { unsigned short u[8]; bf16x8 v; } r;
#pragma unroll
    for (int j = 0; j < 8; ++j) r.u[j] = tile[s * 8 + j][d];
    *(bf16x8*)(Vt + ((size_t)bh * DK_ + d) * T_ + t0 + s * 8) = r.v;
  }
}

// ---------------- flash attention, swapped-operand 32x32, XCD-swizzled, compacted kv ----------------
__global__ __launch_bounds__(256, 2) void attn_kernel(
    const unsigned short* __restrict__ Qp,
    const unsigned short* __restrict__ Kp,
    const unsigned short* __restrict__ Vt,
    const float* __restrict__ maskf,
    const int* __restrict__ nbuf,
    unsigned short* __restrict__ X) {
  const int tid = threadIdx.x, wid = tid >> 6, lane = tid & 63;
  const int la = lane & 31, hi = lane >> 5;
  const int id = blockIdx.x;                  // 0..511
  const int swz = (id & 7) * 64 + (id >> 3);
  const int bh = swz >> 4, qb = swz & 15;
  const int b = bh >> 3, h = bh & 7;
  const int qrow = qb * 128 + wid * 32 + la;
  const int nt = (nbuf[b] + 63) >> 6;         // compacted tile count

  __shared__ __align__(16) unsigned short Ks[2][64 * 64];  // [kv][dk], 16B-slot XOR swizzle
  __shared__ __align__(16) unsigned short Vs[2][64 * 64];  // [d][kv], swizzled
  __shared__ __align__(16) float Ms[2][64];                // mask addend (tail -inf)

  bf16x8 qf[4];
#pragma unroll
  for (int kk = 0; kk < 4; ++kk)
    qf[kk] = *(const bf16x8*)(Qp + (size_t)(b * T_ + qrow) * F_ + h * DK_ + kk * 16 + hi * 8);

  f32x16 oacc[2] = {};
  float mrun = -1e30f, lrun = 0.0f;

  auto stage = [&](int buf, int kv0) {
#pragma unroll
    for (int i = 0; i < 2; ++i) {
      const int ch = i * 256 + tid;
      const int r = ch >> 3, s = ch & 7;
      gload_lds16(Kp + (size_t)(b * T_ + kv0 + r) * F_ + h * DK_ + ((s ^ (r & 7)) * 8),
                  &Ks[buf][(i * 256 + wid * 64) * 8]);
      gload_lds16(Vt + ((size_t)bh * DK_ + r) * T_ + kv0 + ((s ^ (r & 7)) * 8),
                  &Vs[buf][(i * 256 + wid * 64) * 8]);
    }
    if (wid == 0 && lane < 16)
      gload_lds16(maskf + b * T_ + kv0 + lane * 4, &Ms[buf][0]);
  };

  if (nt > 0) {
    stage(0, 0);
    __syncthreads();

    for (int t = 0; t < nt; ++t) {
      const int cur = t & 1;
      if (t < nt - 1) stage(cur ^ 1, (t + 1) * 64);

      bf16x8 kf0[4], kf1[4];
#pragma unroll
      for (int kk = 0; kk < 4; ++kk) {
        kf0[kk] = *(const bf16x8*)&Ks[cur][la * 64 + (((2 * kk + hi) ^ (la & 7)) * 8)];
        kf1[kk] = *(const bf16x8*)&Ks[cur][(32 + la) * 64 + (((2 * kk + hi) ^ (la & 7)) * 8)];
      }
      f32x4 mfv[2][4];
#pragma unroll
      for (int n = 0; n < 2; ++n)
#pragma unroll
        for (int g = 0; g < 4; ++g)
          mfv[n][g] = *(const f32x4*)&Ms[cur][n * 32 + 8 * g + 4 * hi];

      f32x16 s0 = {}, s1 = {};
      __builtin_amdgcn_s_setprio(1);
#pragma unroll
      for (int kk = 0; kk < 4; ++kk) {
        s0 = __builtin_amdgcn_mfma_f32_32x32x16_bf16(kf0[kk], qf[kk], s0, 0, 0, 0);
        s1 = __builtin_amdgcn_mfma_f32_32x32x16_bf16(kf1[kk], qf[kk], s1, 0, 0, 0);
      }
      __builtin_amdgcn_s_setprio(0);

      float mx[16];
#pragma unroll
      for (int r = 0; r < 16; ++r) mx[r] = fmaxf(s0[r], s1[r]);
#pragma unroll
      for (int st = 8; st > 0; st >>= 1)
#pragma unroll
        for (int r = 0; r < st; ++r) mx[r] = fmaxf(mx[r], mx[r + st]);
      const float rmx = fmaxf(mx[0], __shfl_xor(mx[0], 32, 64));

      if (!__all(rmx <= mrun + 8.0f)) {
        const float mnew = fmaxf(mrun, rmx);
        const float alpha = __builtin_amdgcn_exp2f(mrun - mnew);
        lrun *= alpha;
#pragma unroll
        for (int m = 0; m < 2; ++m)
#pragma unroll
          for (int r = 0; r < 16; ++r) oacc[m][r] *= alpha;
        mrun = mnew;
      }

      float p0[16], p1[16];
#pragma unroll
      for (int r = 0; r < 16; ++r) {
        p0[r] = __builtin_amdgcn_exp2f((s0[r] + mfv[0][r >> 2][r & 3]) - mrun);
        p1[r] = __builtin_amdgcn_exp2f((s1[r] + mfv[1][r >> 2][r & 3]) - mrun);
      }
      float sm[16];
#pragma unroll
      for (int r = 0; r < 16; ++r) sm[r] = p0[r] + p1[r];
#pragma unroll
      for (int st = 8; st > 0; st >>= 1)
#pragma unroll
        for (int r = 0; r < st; ++r) sm[r] += sm[r + st];
      lrun += sm[0] + __shfl_xor(sm[0], 32, 64);

      unsigned lowr[2][2][2], uppr[2][2][2];
#pragma unroll
      for (int n = 0; n < 2; ++n)
#pragma unroll
        for (int gg = 0; gg < 2; ++gg)
#pragma unroll
          for (int hh = 0; hh < 2; ++hh) {
            const float* ps = (n == 0) ? p0 : p1;
            unsigned xE = cvtpk(ps[4 * (2 * gg) + 2 * hh], ps[4 * (2 * gg) + 2 * hh + 1]);
            unsigned xO = cvtpk(ps[4 * (2 * gg + 1) + 2 * hh], ps[4 * (2 * gg + 1) + 2 * hh + 1]);
            asm("v_permlane32_swap_b32 %0, %1" : "+v"(xE), "+v"(xO));
            lowr[n][gg][hh] = xE;
            uppr[n][gg][hh] = xO;
          }

#pragma unroll
      for (int kt = 0; kt < 4; ++kt) {
        const int n = kt >> 1, gg = kt & 1;
        union { unsigned w[4]; bf16x8 v; } pf;
        pf.w[0] = lowr[n][gg][0]; pf.w[1] = lowr[n][gg][1];
        pf.w[2] = uppr[n][gg][0]; pf.w[3] = uppr[n][gg][1];
        __builtin_amdgcn_s_setprio(1);
#pragma unroll
        for (int m = 0; m < 2; ++m) {
          bf16x8 vfr = *(const bf16x8*)&Vs[cur][(m * 32 + la) * 64 + (((2 * kt + hi) ^ (la & 7)) * 8)];
          oacc[m] = __builtin_amdgcn_mfma_f32_32x32x16_bf16(vfr, pf.v, oacc[m], 0, 0, 0);
        }
        __builtin_amdgcn_s_setprio(0);
      }
      __syncthreads();
    }
  }

  const float inv = 1.0f / fmaxf(lrun, 1e-37f);
#pragma unroll
  for (int m = 0; m < 2; ++m)
#pragma unroll
    for (int g = 0; g < 4; ++g) {
      union { unsigned short u[4]; s16x4 v; } ov;
#pragma unroll
      for (int j = 0; j < 4; ++j) ov.u[j] = f2bf(oacc[m][4 * g + j] * inv);
      *(s16x4*)(X + (size_t)(b * T_ + qrow) * F_ + h * DK_ + m * 32 + 8 * g + 4 * hi) = ov.v;
    }
}

// ---------------- launcher ----------------
extern "C" void kernel_launch(void* const* d_in, const int* in_sizes, int n_in,
                              void* d_out, int out_size, void* d_ws, size_t ws_size,
                              hipStream_t stream) {
  const float* q  = (const float*)d_in[0];
  const float* k  = (const float*)d_in[1];
  const float* v  = (const float*)d_in[2];
  const int* mask = (const int*)d_in[3];
  const float* Wq = (const float*)d_in[4];
  const float* bq = (const float*)d_in[5];
  const float* Wk = (const float*)d_in[6];
  const float* bk = (const float*)d_in[7];
  const float* Wv = (const float*)d_in[8];
  const float* bv = (const float*)d_in[9];
  const float* Wo = (const float*)d_in[10];
  const float* bo = (const float*)d_in[11];
  float* out = (float*)d_out;

  unsigned short* ws = (unsigned short*)d_ws;
  unsigned short* wts  = ws;                               // 4*F*F = 1,048,576 us
  unsigned short* proj = wts + (size_t)4 * F_ * F_;        // 3*BT*F (Q,K,V)
  unsigned short* vt   = proj + (size_t)3 * BT_ * F_;      // BT*F
  unsigned short* xbuf = vt + (size_t)BT_ * F_;            // BT*F
  unsigned short* kc   = xbuf + (size_t)BT_ * F_;          // BT*F (compacted K)
  float* maskf = (float*)(kc + (size_t)BT_ * F_);          // B*T f32
  int* invidx  = (int*)(maskf + BT_);                      // B*T int
  int* nbuf    = invidx + BT_;                             // B int

  const float kQScale = 0.18033688011112042f;  // (1/sqrt(64)) * log2(e)

  convert_w<<<dim3(128, 4, 1), 256, 0, stream>>>(Wq, Wk, Wv, Wo, wts);
  scan_mask<<<dim3(B_, 1, 1), 256, 0, stream>>>(mask, invidx, nbuf);
  gemm_bt<true, false><<<dim3(768, 1, 1), 256, 0, stream>>>(
      q, k, v, nullptr, wts, bq, bk, bv, proj, nullptr, kQScale);
  gather_k<<<dim3(32, B_, 1), 256, 0, stream>>>(
      proj + (size_t)BT_ * F_, invidx, nbuf, kc, maskf);
  transpose_v<<<dim3(32, 32, 1), 256, 0, stream>>>(
      proj + (size_t)2 * BT_ * F_, invidx, nbuf, vt);
  attn_kernel<<<dim3(512, 1, 1), 256, 0, stream>>>(
      proj, kc, vt, maskf, nbuf, xbuf);
  gemm_bt<false, true><<<dim3(256, 1, 1), 256, 0, stream>>>(
      nullptr, nullptr, nullptr, xbuf, wts + (size_t)3 * F_ * F_, bo, bo, bo, nullptr, out, 1.0f);
}

// Round 9
// 92.552 us; speedup vs baseline: 2.0825x; 1.1025x over previous
//
#include <hip/hip_runtime.h>
#include <hip/hip_bf16.h>
#include <stdint.h>

#define B_ 4
#define T_ 2048
#define F_ 512
#define H_ 8
#define DK_ 64
#define BT_ (B_*T_)   // 8192

typedef short bf16x8 __attribute__((ext_vector_type(8)));
typedef short s16x4 __attribute__((ext_vector_type(4)));
typedef float f32x4 __attribute__((ext_vector_type(4)));
typedef float f32x16 __attribute__((ext_vector_type(16)));

__device__ __forceinline__ unsigned short f2bf(float f) {
  union { float f; unsigned u; } v; v.f = f;
  return (unsigned short)((v.u + 0x7fffu + ((v.u >> 16) & 1u)) >> 16);
}

__device__ __forceinline__ unsigned cvtpk(float lo, float hi) {
  unsigned w;
  asm("v_cvt_pk_bf16_f32 %0, %1, %2" : "=v"(w) : "v"(lo), "v"(hi));
  return w;
}

__device__ __forceinline__ void gload_lds16(const void* g, void* l) {
  __builtin_amdgcn_global_load_lds((const __attribute__((address_space(1))) void*)g,
                                   (__attribute__((address_space(3))) void*)l, 16, 0, 0);
}

// ---------------- weight conversion fp32 -> bf16 ----------------
__global__ void convert_w(const float* __restrict__ wq, const float* __restrict__ wk,
                          const float* __restrict__ wv, const float* __restrict__ wo,
                          unsigned short* __restrict__ dst) {
  const int seg = blockIdx.y;
  const float* src = seg == 0 ? wq : (seg == 1 ? wk : (seg == 2 ? wv : wo));
  unsigned short* out = dst + (size_t)seg * F_ * F_;
  const int idx = (blockIdx.x * 256 + threadIdx.x) * 8;   // 128 blocks * 256 * 8 = 262144 exact
  float4 a = *(const float4*)(src + idx);
  float4 b = *(const float4*)(src + idx + 4);
  union { unsigned w[4]; bf16x8 v; } t;
  t.w[0] = cvtpk(a.x, a.y); t.w[1] = cvtpk(a.z, a.w);
  t.w[2] = cvtpk(b.x, b.y); t.w[3] = cvtpk(b.z, b.w);
  *(bf16x8*)(out + idx) = t.v;
}

// ---------------- mask scan: per-batch prefix sum -> invidx, nb, compacted mask addend ----------------
__global__ void scan_mask(const int* __restrict__ mask, int* __restrict__ invidx,
                          int* __restrict__ nbuf, float* __restrict__ maskf) {
  const int b = blockIdx.x, tid = threadIdx.x;
  __shared__ int cnt[256];
  const int base = b * T_ + tid * 8;
  int4 a = *(const int4*)(mask + base);
  int4 d = *(const int4*)(mask + base + 4);
  int m[8] = {a.x, a.y, a.z, a.w, d.x, d.y, d.z, d.w};
  int c = 0;
#pragma unroll
  for (int i = 0; i < 8; ++i) c += (m[i] != 0);
  cnt[tid] = c;
  __syncthreads();
  for (int off = 1; off < 256; off <<= 1) {
    int v = (tid >= off) ? cnt[tid - off] : 0;
    __syncthreads();
    cnt[tid] += v;
    __syncthreads();
  }
  int excl = cnt[tid] - c;
#pragma unroll
  for (int i = 0; i < 8; ++i)
    if (m[i]) { invidx[b * T_ + excl] = tid * 8 + i; ++excl; }
  const int nb = cnt[255];
  if (tid == 255) nbuf[b] = nb;
#pragma unroll
  for (int i = 0; i < 8; ++i) {
    const int j = tid * 8 + i;
    maskf[b * T_ + j] = (j < nb) ? 0.0f : -__builtin_inff();
  }
}

// ---------------- fused QKV projection GEMM: C = (A @ W^T + bias) * sc ----------------
// 128x128 tile, 4 waves (2x2), BK=64, single-buffered 32 KB LDS, XOR-swizzled slots
// (slot s at row r stored at s^(r&7); reads conflict-free since row&7 == lr&7).
// A (fp32) is register-prefetched one K-step ahead (issued under the MFMA phase).
// p=0: Q (direct rows, pre-scaled). p=1/2: K/V with fused mask-gather -> compacted rows.
__global__ __launch_bounds__(256, 3) void gemm_qkv(
    const float* __restrict__ qin, const float* __restrict__ kin, const float* __restrict__ vin,
    const unsigned short* __restrict__ Wbase,
    const float* __restrict__ bq, const float* __restrict__ bk, const float* __restrict__ bv,
    const int* __restrict__ invidx, const int* __restrict__ nbuf,
    unsigned short* __restrict__ projq, unsigned short* __restrict__ kc,
    unsigned short* __restrict__ vc, float qscale) {
  const int id = blockIdx.x;
  const int p = id >> 8, l = id & 255;
  const int tid = threadIdx.x;
  const int wid = tid >> 6, lane = tid & 63;
  const int lr = lane & 15, lg = lane >> 4;
  const int wr = wid >> 1, wc = wid & 1;
  const int n0 = (l & 3) * 128;

  const float* Af;
  const float* bias;
  unsigned short* outp;
  float sc = 1.0f;
  int obase, b = 0, nb = T_;
  if (p == 0) {
    obase = (l >> 2) * 128;
    Af = qin; bias = bq; outp = projq; sc = qscale;
  } else {
    b = l >> 6;
    const int j0 = ((l >> 2) & 15) * 128;
    nb = nbuf[b];
    if (j0 >= ((nb + 63) & ~63)) return;   // tile entirely beyond compacted range
    obase = b * T_ + j0;
    Af = (p == 1) ? kin : vin;
    bias = (p == 1) ? bk : bv;
    outp = (p == 1) ? kc : vc;
  }
  const unsigned short* W = Wbase + (size_t)p * F_ * F_;

  __shared__ __align__(16) unsigned short As[128 * 64];
  __shared__ __align__(16) unsigned short Bs[128 * 64];

  // per-thread staging coords (4 slots of 16B): ch = i*256+tid -> r = ch>>3, s = ch&7
  int srcrow[4];
#pragma unroll
  for (int i = 0; i < 4; ++i) {
    const int r = (i * 256 + tid) >> 3;
    if (p == 0) srcrow[i] = obase + r;
    else {
      int j = (obase - b * T_) + r;
      if (j >= nb) j = nb - 1;               // clamp: duplicate a real row (masked out later)
      srcrow[i] = b * T_ + invidx[b * T_ + j];
    }
  }

  float4 aR[4][2];
  auto loadA = [&](int k0) {
#pragma unroll
    for (int i = 0; i < 4; ++i) {
      const int s = (i * 256 + tid) & 7;
      const float* sp = Af + (size_t)srcrow[i] * F_ + k0 + s * 8;
      aR[i][0] = *(const float4*)sp;
      aR[i][1] = *(const float4*)(sp + 4);
    }
  };
  auto writeA = [&]() {
#pragma unroll
    for (int i = 0; i < 4; ++i) {
      const int ch = i * 256 + tid;
      const int r = ch >> 3, s = ch & 7;
      union { unsigned w[4]; bf16x8 v; } t;
      t.w[0] = cvtpk(aR[i][0].x, aR[i][0].y); t.w[1] = cvtpk(aR[i][0].z, aR[i][0].w);
      t.w[2] = cvtpk(aR[i][1].x, aR[i][1].y); t.w[3] = cvtpk(aR[i][1].z, aR[i][1].w);
      *(bf16x8*)&As[r * 64 + ((s ^ (r & 7)) * 8)] = t.v;
    }
  };
  auto stageB = [&](int k0) {
#pragma unroll
    for (int i = 0; i < 4; ++i) {
      const int ch = i * 256 + tid;
      const int r = ch >> 3, s = ch & 7;
      gload_lds16(W + (size_t)(n0 + r) * F_ + k0 + ((s ^ (r & 7)) * 8),
                  &Bs[(i * 256 + wid * 64) * 8]);
    }
  };

  f32x4 acc[4][4] = {};
  loadA(0);
  for (int k0 = 0; k0 < F_; k0 += 64) {
    stageB(k0);
    writeA();
    __syncthreads();                         // B staged + A written
    if (k0 + 64 < F_) loadA(k0 + 64);        // prefetch next A under compute

#pragma unroll
    for (int kk = 0; kk < 2; ++kk) {
      bf16x8 af[4], bf[4];
      const int slotA = (kk * 4 + lg) ^ (lr & 7);
#pragma unroll
      for (int m = 0; m < 4; ++m)
        af[m] = *(const bf16x8*)&As[(wr * 64 + m * 16 + lr) * 64 + slotA * 8];
#pragma unroll
      for (int n = 0; n < 4; ++n)
        bf[n] = *(const bf16x8*)&Bs[(wc * 64 + n * 16 + lr) * 64 + slotA * 8];
#pragma unroll
      for (int m = 0; m < 4; ++m)
#pragma unroll
        for (int n = 0; n < 4; ++n)
          acc[m][n] = __builtin_amdgcn_mfma_f32_16x16x32_bf16(af[m], bf[n], acc[m][n], 0, 0, 0);
    }
    __syncthreads();                         // reads done before next-step overwrite
  }

#pragma unroll
  for (int n = 0; n < 4; ++n) {
    const int col = n0 + wc * 64 + n * 16 + lr;
    const float bvv = bias[col];
#pragma unroll
    for (int m = 0; m < 4; ++m) {
      const int rbase = obase + wr * 64 + m * 16 + lg * 4;
#pragma unroll
      for (int j = 0; j < 4; ++j)
        outp[(size_t)(rbase + j) * F_ + col] = f2bf((acc[m][n][j] + bvv) * sc);
    }
  }
}

// ---------------- output projection GEMM (bf16 A, fp32 out), same BK=64 structure ----------------
__global__ __launch_bounds__(256, 3) void gemm_out(
    const unsigned short* __restrict__ Abf, const unsigned short* __restrict__ W,
    const float* __restrict__ bias, float* __restrict__ outf) {
  const int l = blockIdx.x;
  const int m0 = (l >> 2) * 128, n0 = (l & 3) * 128;
  const int tid = threadIdx.x;
  const int wid = tid >> 6, lane = tid & 63;
  const int lr = lane & 15, lg = lane >> 4;
  const int wr = wid >> 1, wc = wid & 1;

  __shared__ __align__(16) unsigned short As[128 * 64];
  __shared__ __align__(16) unsigned short Bs[128 * 64];

  auto stage = [&](int k0) {
#pragma unroll
    for (int i = 0; i < 4; ++i) {
      const int ch = i * 256 + tid;
      const int r = ch >> 3, s = ch & 7;
      const int ks = ((s ^ (r & 7)) * 8);
      gload_lds16(Abf + (size_t)(m0 + r) * F_ + k0 + ks, &As[(i * 256 + wid * 64) * 8]);
      gload_lds16(W + (size_t)(n0 + r) * F_ + k0 + ks, &Bs[(i * 256 + wid * 64) * 8]);
    }
  };

  f32x4 acc[4][4] = {};
  for (int k0 = 0; k0 < F_; k0 += 64) {
    stage(k0);
    __syncthreads();
#pragma unroll
    for (int kk = 0; kk < 2; ++kk) {
      bf16x8 af[4], bf[4];
      const int slotA = (kk * 4 + lg) ^ (lr & 7);
#pragma unroll
      for (int m = 0; m < 4; ++m)
        af[m] = *(const bf16x8*)&As[(wr * 64 + m * 16 + lr) * 64 + slotA * 8];
#pragma unroll
      for (int n = 0; n < 4; ++n)
        bf[n] = *(const bf16x8*)&Bs[(wc * 64 + n * 16 + lr) * 64 + slotA * 8];
#pragma unroll
      for (int m = 0; m < 4; ++m)
#pragma unroll
        for (int n = 0; n < 4; ++n)
          acc[m][n] = __builtin_amdgcn_mfma_f32_16x16x32_bf16(af[m], bf[n], acc[m][n], 0, 0, 0);
    }
    __syncthreads();
  }

#pragma unroll
  for (int n = 0; n < 4; ++n) {
    const int col = n0 + wc * 64 + n * 16 + lr;
    const float bvv = bias[col];
#pragma unroll
    for (int m = 0; m < 4; ++m) {
      const int rbase = m0 + wr * 64 + m * 16 + lg * 4;
#pragma unroll
      for (int j = 0; j < 4; ++j)
        outf[(size_t)(rbase + j) * F_ + col] = acc[m][n][j] + bvv;
    }
  }
}

// ---------------- transpose V: compacted rows (B,T,F)-per-head -> [BH][DK][Tc] ----------------
__global__ void transpose_v(const unsigned short* __restrict__ Vc,
                            const int* __restrict__ nbuf,
                            unsigned short* __restrict__ Vt) {
  const int bh = blockIdx.y, b = bh >> 3, h = bh & 7;
  const int t0 = blockIdx.x * 64;
  const int tid = threadIdx.x;
  const int nb = nbuf[b];
  const int ce = (nb + 63) & ~63;
  if (t0 >= ce) return;
  __shared__ __align__(16) unsigned short tile[64][72];

#pragma unroll
  for (int i = 0; i < 2; ++i) {
    const int ch = i * 256 + tid;          // 512 chunks of 8
    const int t = ch >> 3, s = ch & 7;
    bf16x8 v = {};
    if (t0 + t < nb)
      v = *(const bf16x8*)(Vc + (size_t)(b * T_ + t0 + t) * F_ + h * DK_ + s * 8);
    *(bf16x8*)&tile[t][s * 8] = v;
  }
  __syncthreads();
#pragma unroll
  for (int i = 0; i < 2; ++i) {
    const int ch = i * 256 + tid;
    const int d = ch >> 3, s = ch & 7;
    union { unsigned short u[8]; bf16x8 v; } r;
#pragma unroll
    for (int j = 0; j < 8; ++j) r.u[j] = tile[s * 8 + j][d];
    *(bf16x8*)(Vt + ((size_t)bh * DK_ + d) * T_ + t0 + s * 8) = r.v;
  }
}

// ---------------- flash attention, swapped-operand 32x32, XCD-swizzled, compacted kv ----------------
__global__ __launch_bounds__(256, 2) void attn_kernel(
    const unsigned short* __restrict__ Qp,
    const unsigned short* __restrict__ Kp,
    const unsigned short* __restrict__ Vt,
    const float* __restrict__ maskf,
    const int* __restrict__ nbuf,
    unsigned short* __restrict__ X) {
  const int tid = threadIdx.x, wid = tid >> 6, lane = tid & 63;
  const int la = lane & 31, hi = lane >> 5;
  const int id = blockIdx.x;                  // 0..511
  const int swz = (id & 7) * 64 + (id >> 3);
  const int bh = swz >> 4, qb = swz & 15;
  const int b = bh >> 3, h = bh & 7;
  const int qrow = qb * 128 + wid * 32 + la;
  const int nt = (nbuf[b] + 63) >> 6;         // compacted tile count

  __shared__ __align__(16) unsigned short Ks[2][64 * 64];  // [kv][dk], 16B-slot XOR swizzle
  __shared__ __align__(16) unsigned short Vs[2][64 * 64];  // [d][kv], swizzled
  __shared__ __align__(16) float Ms[2][64];                // mask addend (tail -inf)

  bf16x8 qf[4];
#pragma unroll
  for (int kk = 0; kk < 4; ++kk)
    qf[kk] = *(const bf16x8*)(Qp + (size_t)(b * T_ + qrow) * F_ + h * DK_ + kk * 16 + hi * 8);

  f32x16 oacc[2] = {};
  float mrun = -1e30f, lrun = 0.0f;

  auto stage = [&](int buf, int kv0) {
#pragma unroll
    for (int i = 0; i < 2; ++i) {
      const int ch = i * 256 + tid;
      const int r = ch >> 3, s = ch & 7;
      gload_lds16(Kp + (size_t)(b * T_ + kv0 + r) * F_ + h * DK_ + ((s ^ (r & 7)) * 8),
                  &Ks[buf][(i * 256 + wid * 64) * 8]);
      gload_lds16(Vt + ((size_t)bh * DK_ + r) * T_ + kv0 + ((s ^ (r & 7)) * 8),
                  &Vs[buf][(i * 256 + wid * 64) * 8]);
    }
    if (wid == 0 && lane < 16)
      gload_lds16(maskf + b * T_ + kv0 + lane * 4, &Ms[buf][0]);
  };

  if (nt > 0) {
    stage(0, 0);
    __syncthreads();

    for (int t = 0; t < nt; ++t) {
      const int cur = t & 1;
      if (t < nt - 1) stage(cur ^ 1, (t + 1) * 64);

      bf16x8 kf0[4], kf1[4];
#pragma unroll
      for (int kk = 0; kk < 4; ++kk) {
        kf0[kk] = *(const bf16x8*)&Ks[cur][la * 64 + (((2 * kk + hi) ^ (la & 7)) * 8)];
        kf1[kk] = *(const bf16x8*)&Ks[cur][(32 + la) * 64 + (((2 * kk + hi) ^ (la & 7)) * 8)];
      }
      f32x4 mfv[2][4];
#pragma unroll
      for (int n = 0; n < 2; ++n)
#pragma unroll
        for (int g = 0; g < 4; ++g)
          mfv[n][g] = *(const f32x4*)&Ms[cur][n * 32 + 8 * g + 4 * hi];

      f32x16 s0 = {}, s1 = {};
      __builtin_amdgcn_s_setprio(1);
#pragma unroll
      for (int kk = 0; kk < 4; ++kk) {
        s0 = __builtin_amdgcn_mfma_f32_32x32x16_bf16(kf0[kk], qf[kk], s0, 0, 0, 0);
        s1 = __builtin_amdgcn_mfma_f32_32x32x16_bf16(kf1[kk], qf[kk], s1, 0, 0, 0);
      }
      __builtin_amdgcn_s_setprio(0);

      float mx[16];
#pragma unroll
      for (int r = 0; r < 16; ++r) mx[r] = fmaxf(s0[r], s1[r]);
#pragma unroll
      for (int st = 8; st > 0; st >>= 1)
#pragma unroll
        for (int r = 0; r < st; ++r) mx[r] = fmaxf(mx[r], mx[r + st]);
      const float rmx = fmaxf(mx[0], __shfl_xor(mx[0], 32, 64));

      if (!__all(rmx <= mrun + 8.0f)) {
        const float mnew = fmaxf(mrun, rmx);
        const float alpha = __builtin_amdgcn_exp2f(mrun - mnew);
        lrun *= alpha;
#pragma unroll
        for (int m = 0; m < 2; ++m)
#pragma unroll
          for (int r = 0; r < 16; ++r) oacc[m][r] *= alpha;
        mrun = mnew;
      }

      float p0[16], p1[16];
#pragma unroll
      for (int r = 0; r < 16; ++r) {
        p0[r] = __builtin_amdgcn_exp2f((s0[r] + mfv[0][r >> 2][r & 3]) - mrun);
        p1[r] = __builtin_amdgcn_exp2f((s1[r] + mfv[1][r >> 2][r & 3]) - mrun);
      }
      float sm[16];
#pragma unroll
      for (int r = 0; r < 16; ++r) sm[r] = p0[r] + p1[r];
#pragma unroll
      for (int st = 8; st > 0; st >>= 1)
#pragma unroll
        for (int r = 0; r < st; ++r) sm[r] += sm[r + st];
      lrun += sm[0] + __shfl_xor(sm[0], 32, 64);

      unsigned lowr[2][2][2], uppr[2][2][2];
#pragma unroll
      for (int n = 0; n < 2; ++n)
#pragma unroll
        for (int gg = 0; gg < 2; ++gg)
#pragma unroll
          for (int hh = 0; hh < 2; ++hh) {
            const float* ps = (n == 0) ? p0 : p1;
            unsigned xE = cvtpk(ps[4 * (2 * gg) + 2 * hh], ps[4 * (2 * gg) + 2 * hh + 1]);
            unsigned xO = cvtpk(ps[4 * (2 * gg + 1) + 2 * hh], ps[4 * (2 * gg + 1) + 2 * hh + 1]);
            asm("v_permlane32_swap_b32 %0, %1" : "+v"(xE), "+v"(xO));
            lowr[n][gg][hh] = xE;
            uppr[n][gg][hh] = xO;
          }

#pragma unroll
      for (int kt = 0; kt < 4; ++kt) {
        const int n = kt >> 1, gg = kt & 1;
        union { unsigned w[4]; bf16x8 v; } pf;
        pf.w[0] = lowr[n][gg][0]; pf.w[1] = lowr[n][gg][1];
        pf.w[2] = uppr[n][gg][0]; pf.w[3] = uppr[n][gg][1];
        __builtin_amdgcn_s_setprio(1);
#pragma unroll
        for (int m = 0; m < 2; ++m) {
          bf16x8 vfr = *(const bf16x8*)&Vs[cur][(m * 32 + la) * 64 + (((2 * kt + hi) ^ (la & 7)) * 8)];
          oacc[m] = __builtin_amdgcn_mfma_f32_32x32x16_bf16(vfr, pf.v, oacc[m], 0, 0, 0);
        }
        __builtin_amdgcn_s_setprio(0);
      }
      __syncthreads();
    }
  }

  const float inv = 1.0f / fmaxf(lrun, 1e-37f);
#pragma unroll
  for (int m = 0; m < 2; ++m)
#pragma unroll
    for (int g = 0; g < 4; ++g) {
      union { unsigned short u[4]; s16x4 v; } ov;
#pragma unroll
      for (int j = 0; j < 4; ++j) ov.u[j] = f2bf(oacc[m][4 * g + j] * inv);
      *(s16x4*)(X + (size_t)(b * T_ + qrow) * F_ + h * DK_ + m * 32 + 8 * g + 4 * hi) = ov.v;
    }
}

// ---------------- launcher ----------------
extern "C" void kernel_launch(void* const* d_in, const int* in_sizes, int n_in,
                              void* d_out, int out_size, void* d_ws, size_t ws_size,
                              hipStream_t stream) {
  const float* q  = (const float*)d_in[0];
  const float* k  = (const float*)d_in[1];
  const float* v  = (const float*)d_in[2];
  const int* mask = (const int*)d_in[3];
  const float* Wq = (const float*)d_in[4];
  const float* bq = (const float*)d_in[5];
  const float* Wk = (const float*)d_in[6];
  const float* bk = (const float*)d_in[7];
  const float* Wv = (const float*)d_in[8];
  const float* bv = (const float*)d_in[9];
  const float* Wo = (const float*)d_in[10];
  const float* bo = (const float*)d_in[11];
  float* out = (float*)d_out;

  unsigned short* ws = (unsigned short*)d_ws;
  unsigned short* wts   = ws;                               // 4*F*F = 1,048,576 us
  unsigned short* projq = wts + (size_t)4 * F_ * F_;        // BT*F (Q)
  unsigned short* kc    = projq + (size_t)BT_ * F_;         // BT*F (compacted K)
  unsigned short* vc    = kc + (size_t)BT_ * F_;            // BT*F (compacted V)
  unsigned short* vt    = vc + (size_t)BT_ * F_;            // BT*F (V^T per head)
  unsigned short* xbuf  = vt + (size_t)BT_ * F_;            // BT*F (attn output)
  float* maskf = (float*)(xbuf + (size_t)BT_ * F_);         // B*T f32
  int* invidx  = (int*)(maskf + BT_);                       // B*T int
  int* nbuf    = invidx + BT_;                              // B int

  const float kQScale = 0.18033688011112042f;  // (1/sqrt(64)) * log2(e)

  convert_w<<<dim3(128, 4, 1), 256, 0, stream>>>(Wq, Wk, Wv, Wo, wts);
  scan_mask<<<dim3(B_, 1, 1), 256, 0, stream>>>(mask, invidx, nbuf, maskf);
  gemm_qkv<<<dim3(768, 1, 1), 256, 0, stream>>>(
      q, k, v, wts, bq, bk, bv, invidx, nbuf, projq, kc, vc, kQScale);
  transpose_v<<<dim3(32, 32, 1), 256, 0, stream>>>(vc, nbuf, vt);
  attn_kernel<<<dim3(512, 1, 1), 256, 0, stream>>>(
      projq, kc, vt, maskf, nbuf, xbuf);
  gemm_out<<<dim3(256, 1, 1), 256, 0, stream>>>(
      xbuf, wts + (size_t)3 * F_ * F_, bo, out);
}

// Round 10
// 83.602 us; speedup vs baseline: 2.3055x; 1.1071x over previous
//
#include <hip/hip_runtime.h>
#include <hip/hip_bf16.h>
#include <stdint.h>

#define B_ 4
#define T_ 2048
#define F_ 512
#define H_ 8
#define DK_ 64
#define BT_ (B_*T_)   // 8192

typedef short bf16x8 __attribute__((ext_vector_type(8)));
typedef short s16x4 __attribute__((ext_vector_type(4)));
typedef float f32x4 __attribute__((ext_vector_type(4)));
typedef float f32x16 __attribute__((ext_vector_type(16)));

__device__ __forceinline__ unsigned short f2bf(float f) {
  union { float f; unsigned u; } v; v.f = f;
  return (unsigned short)((v.u + 0x7fffu + ((v.u >> 16) & 1u)) >> 16);
}

__device__ __forceinline__ unsigned cvtpk(float lo, float hi) {
  unsigned w;
  asm("v_cvt_pk_bf16_f32 %0, %1, %2" : "=v"(w) : "v"(lo), "v"(hi));
  return w;
}

__device__ __forceinline__ void gload_lds16(const void* g, void* l) {
  __builtin_amdgcn_global_load_lds((const __attribute__((address_space(1))) void*)g,
                                   (__attribute__((address_space(3))) void*)l, 16, 0, 0);
}

// ---------------- fused: weight fp32->bf16 conversion + mask scan ----------------
__global__ void convert_scan(const float* __restrict__ wq, const float* __restrict__ wk,
                             const float* __restrict__ wv, const float* __restrict__ wo,
                             const int* __restrict__ mask,
                             unsigned short* __restrict__ dst, int* __restrict__ invidx,
                             int* __restrict__ nbuf, float* __restrict__ maskf) {
  const int seg = blockIdx.y;
  const int tid = threadIdx.x;
  if (seg == 4) {
    if (blockIdx.x >= 4) return;
    const int b = blockIdx.x;
    __shared__ int cnt[256];
    const int base = b * T_ + tid * 8;
    int4 a = *(const int4*)(mask + base);
    int4 d = *(const int4*)(mask + base + 4);
    int m[8] = {a.x, a.y, a.z, a.w, d.x, d.y, d.z, d.w};
    int c = 0;
#pragma unroll
    for (int i = 0; i < 8; ++i) c += (m[i] != 0);
    cnt[tid] = c;
    __syncthreads();
    for (int off = 1; off < 256; off <<= 1) {
      int v = (tid >= off) ? cnt[tid - off] : 0;
      __syncthreads();
      cnt[tid] += v;
      __syncthreads();
    }
    int excl = cnt[tid] - c;
#pragma unroll
    for (int i = 0; i < 8; ++i)
      if (m[i]) { invidx[b * T_ + excl] = tid * 8 + i; ++excl; }
    const int nb = cnt[255];
    if (tid == 255) nbuf[b] = nb;
#pragma unroll
    for (int i = 0; i < 8; ++i) {
      const int j = tid * 8 + i;
      maskf[b * T_ + j] = (j < nb) ? 0.0f : -__builtin_inff();
    }
    return;
  }
  const float* src = seg == 0 ? wq : (seg == 1 ? wk : (seg == 2 ? wv : wo));
  unsigned short* out = dst + (size_t)seg * F_ * F_;
  const int idx = (blockIdx.x * 256 + tid) * 8;
  float4 a = *(const float4*)(src + idx);
  float4 b = *(const float4*)(src + idx + 4);
  union { unsigned w[4]; bf16x8 v; } t;
  t.w[0] = cvtpk(a.x, a.y); t.w[1] = cvtpk(a.z, a.w);
  t.w[2] = cvtpk(b.x, b.y); t.w[3] = cvtpk(b.z, b.w);
  *(bf16x8*)(out + idx) = t.v;
}

// ---------------- fused QKV projection GEMM ----------------
// p=0: Q rows (pre-scaled); p=1: K mask-gathered -> compacted kc (row-major);
// p=2: V mask-gathered -> Vt [BH][DK][Tc] written TRANSPOSED in the epilogue.
__global__ __launch_bounds__(256, 3) void gemm_qkv(
    const float* __restrict__ qin, const float* __restrict__ kin, const float* __restrict__ vin,
    const unsigned short* __restrict__ Wbase,
    const float* __restrict__ bq, const float* __restrict__ bk, const float* __restrict__ bv,
    const int* __restrict__ invidx, const int* __restrict__ nbuf,
    unsigned short* __restrict__ projq, unsigned short* __restrict__ kc,
    unsigned short* __restrict__ vt, float qscale) {
  const int id = blockIdx.x;
  const int p = id >> 8, l = id & 255;
  const int tid = threadIdx.x;
  const int wid = tid >> 6, lane = tid & 63;
  const int lr = lane & 15, lg = lane >> 4;
  const int wr = wid >> 1, wc = wid & 1;
  const int n0 = (l & 3) * 128;

  const float* Af;
  const float* bias;
  float sc = 1.0f;
  int obase, j0 = 0, b = 0, nb = T_;
  if (p == 0) {
    obase = (l >> 2) * 128;
    Af = qin; bias = bq; sc = qscale;
  } else {
    b = l >> 6;
    j0 = ((l >> 2) & 15) * 128;
    nb = nbuf[b];
    if (j0 >= ((nb + 63) & ~63)) return;   // tile entirely beyond compacted range
    obase = b * T_ + j0;
    Af = (p == 1) ? kin : vin;
    bias = (p == 1) ? bk : bv;
  }
  const unsigned short* W = Wbase + (size_t)p * F_ * F_;

  __shared__ __align__(16) unsigned short As[128 * 64];
  __shared__ __align__(16) unsigned short Bs[128 * 64];

  int srcrow[4];
#pragma unroll
  for (int i = 0; i < 4; ++i) {
    const int r = (i * 256 + tid) >> 3;
    if (p == 0) srcrow[i] = obase + r;
    else {
      int j = j0 + r;
      if (j >= nb) j = nb - 1;               // clamp: duplicate a real row (masked later)
      srcrow[i] = b * T_ + invidx[b * T_ + j];
    }
  }

  float4 aR[4][2];
  auto loadA = [&](int k0) {
#pragma unroll
    for (int i = 0; i < 4; ++i) {
      const int s = (i * 256 + tid) & 7;
      const float* sp = Af + (size_t)srcrow[i] * F_ + k0 + s * 8;
      aR[i][0] = *(const float4*)sp;
      aR[i][1] = *(const float4*)(sp + 4);
    }
  };
  auto writeA = [&]() {
#pragma unroll
    for (int i = 0; i < 4; ++i) {
      const int ch = i * 256 + tid;
      const int r = ch >> 3, s = ch & 7;
      union { unsigned w[4]; bf16x8 v; } t;
      t.w[0] = cvtpk(aR[i][0].x, aR[i][0].y); t.w[1] = cvtpk(aR[i][0].z, aR[i][0].w);
      t.w[2] = cvtpk(aR[i][1].x, aR[i][1].y); t.w[3] = cvtpk(aR[i][1].z, aR[i][1].w);
      *(bf16x8*)&As[r * 64 + ((s ^ (r & 7)) * 8)] = t.v;
    }
  };
  auto stageB = [&](int k0) {
#pragma unroll
    for (int i = 0; i < 4; ++i) {
      const int ch = i * 256 + tid;
      const int r = ch >> 3, s = ch & 7;
      gload_lds16(W + (size_t)(n0 + r) * F_ + k0 + ((s ^ (r & 7)) * 8),
                  &Bs[(i * 256 + wid * 64) * 8]);
    }
  };

  f32x4 acc[4][4] = {};
  loadA(0);
  for (int k0 = 0; k0 < F_; k0 += 64) {
    stageB(k0);
    writeA();
    __syncthreads();
    if (k0 + 64 < F_) loadA(k0 + 64);

#pragma unroll
    for (int kk = 0; kk < 2; ++kk) {
      bf16x8 af[4], bf[4];
      const int slotA = (kk * 4 + lg) ^ (lr & 7);
#pragma unroll
      for (int m = 0; m < 4; ++m)
        af[m] = *(const bf16x8*)&As[(wr * 64 + m * 16 + lr) * 64 + slotA * 8];
#pragma unroll
      for (int n = 0; n < 4; ++n)
        bf[n] = *(const bf16x8*)&Bs[(wc * 64 + n * 16 + lr) * 64 + slotA * 8];
#pragma unroll
      for (int m = 0; m < 4; ++m)
#pragma unroll
        for (int n = 0; n < 4; ++n)
          acc[m][n] = __builtin_amdgcn_mfma_f32_16x16x32_bf16(af[m], bf[n], acc[m][n], 0, 0, 0);
    }
    __syncthreads();
  }

  if (p == 2) {
    // transposed write: Vt[((b*8 + h)*64 + d)*T + kv],  h = col>>6, d = col&63
#pragma unroll
    for (int n = 0; n < 4; ++n) {
      const int col = n0 + wc * 64 + n * 16 + lr;
      const float bvv = bias[col];
      unsigned short* vrow = vt + ((size_t)(b * 8 + (col >> 6)) * 64 + (col & 63)) * T_;
#pragma unroll
      for (int m = 0; m < 4; ++m) {
        const int kv = j0 + wr * 64 + m * 16 + lg * 4;
        union { unsigned short u[4]; s16x4 v; } ov;
#pragma unroll
        for (int j = 0; j < 4; ++j) ov.u[j] = f2bf(acc[m][n][j] + bvv);
        *(s16x4*)(vrow + kv) = ov.v;
      }
    }
  } else {
    unsigned short* outp = (p == 0) ? projq : kc;
#pragma unroll
    for (int n = 0; n < 4; ++n) {
      const int col = n0 + wc * 64 + n * 16 + lr;
      const float bvv = bias[col];
#pragma unroll
      for (int m = 0; m < 4; ++m) {
        const int rbase = obase + wr * 64 + m * 16 + lg * 4;
#pragma unroll
        for (int j = 0; j < 4; ++j)
          outp[(size_t)(rbase + j) * F_ + col] = f2bf((acc[m][n][j] + bvv) * sc);
      }
    }
  }
}

// ---------------- output projection GEMM (bf16 A, fp32 out) ----------------
__global__ __launch_bounds__(256, 3) void gemm_out(
    const unsigned short* __restrict__ Abf, const unsigned short* __restrict__ W,
    const float* __restrict__ bias, float* __restrict__ outf) {
  const int l = blockIdx.x;
  const int m0 = (l >> 2) * 128, n0 = (l & 3) * 128;
  const int tid = threadIdx.x;
  const int wid = tid >> 6, lane = tid & 63;
  const int lr = lane & 15, lg = lane >> 4;
  const int wr = wid >> 1, wc = wid & 1;

  __shared__ __align__(16) unsigned short As[128 * 64];
  __shared__ __align__(16) unsigned short Bs[128 * 64];

  auto stage = [&](int k0) {
#pragma unroll
    for (int i = 0; i < 4; ++i) {
      const int ch = i * 256 + tid;
      const int r = ch >> 3, s = ch & 7;
      const int ks = ((s ^ (r & 7)) * 8);
      gload_lds16(Abf + (size_t)(m0 + r) * F_ + k0 + ks, &As[(i * 256 + wid * 64) * 8]);
      gload_lds16(W + (size_t)(n0 + r) * F_ + k0 + ks, &Bs[(i * 256 + wid * 64) * 8]);
    }
  };

  f32x4 acc[4][4] = {};
  for (int k0 = 0; k0 < F_; k0 += 64) {
    stage(k0);
    __syncthreads();
#pragma unroll
    for (int kk = 0; kk < 2; ++kk) {
      bf16x8 af[4], bf[4];
      const int slotA = (kk * 4 + lg) ^ (lr & 7);
#pragma unroll
      for (int m = 0; m < 4; ++m)
        af[m] = *(const bf16x8*)&As[(wr * 64 + m * 16 + lr) * 64 + slotA * 8];
#pragma unroll
      for (int n = 0; n < 4; ++n)
        bf[n] = *(const bf16x8*)&Bs[(wc * 64 + n * 16 + lr) * 64 + slotA * 8];
#pragma unroll
      for (int m = 0; m < 4; ++m)
#pragma unroll
        for (int n = 0; n < 4; ++n)
          acc[m][n] = __builtin_amdgcn_mfma_f32_16x16x32_bf16(af[m], bf[n], acc[m][n], 0, 0, 0);
    }
    __syncthreads();
  }

#pragma unroll
  for (int n = 0; n < 4; ++n) {
    const int col = n0 + wc * 64 + n * 16 + lr;
    const float bvv = bias[col];
#pragma unroll
    for (int m = 0; m < 4; ++m) {
      const int rbase = m0 + wr * 64 + m * 16 + lg * 4;
#pragma unroll
      for (int j = 0; j < 4; ++j)
        outf[(size_t)(rbase + j) * F_ + col] = acc[m][n][j] + bvv;
    }
  }
}

// ---------------- flash attention, swapped-operand 32x32, KVBLK=128, compacted kv ----------------
// 4 waves x 32 q-rows = 128 q/block; KV tile 128 (double-buffered 65 KB LDS), 8 tiles typical.
// S^T = mfma(K,Q): lane owns ONE q-row (4x f32x16 S blocks); softmax fully in-register
// (cvt_pk + permlane32_swap). O^T = mfma(V^T, P^T). Q pre-scaled by 0.125*log2e.
__global__ __launch_bounds__(256, 2) void attn_kernel(
    const unsigned short* __restrict__ Qp,
    const unsigned short* __restrict__ Kp,
    const unsigned short* __restrict__ Vt,
    const float* __restrict__ maskf,
    const int* __restrict__ nbuf,
    unsigned short* __restrict__ X) {
  const int tid = threadIdx.x, wid = tid >> 6, lane = tid & 63;
  const int la = lane & 31, hi = lane >> 5;
  const int id = blockIdx.x;                  // 0..511, XCD-aware bijective swizzle
  const int swz = (id & 7) * 64 + (id >> 3);
  const int bh = swz >> 4, qb = swz & 15;
  const int b = bh >> 3, h = bh & 7;
  const int qrow = qb * 128 + wid * 32 + la;
  const int nt = (nbuf[b] + 127) >> 7;        // compacted 128-tile count

  __shared__ __align__(16) unsigned short Ks[2][128 * 64];  // [kv][dk], 8-slot XOR swizzle
  __shared__ __align__(16) unsigned short Vs[2][64 * 128];  // [d][kv], 16-slot XOR swizzle
  __shared__ __align__(16) float Ms[2][128];                // mask addend (tail -inf)

  bf16x8 qf[4];
#pragma unroll
  for (int kk = 0; kk < 4; ++kk)
    qf[kk] = *(const bf16x8*)(Qp + (size_t)(b * T_ + qrow) * F_ + h * DK_ + kk * 16 + hi * 8);

  f32x16 oacc[2] = {};
  float mrun = -1e30f, lrun = 0.0f;

  auto stage = [&](int buf, int kv0) {
#pragma unroll
    for (int i = 0; i < 4; ++i) {
      const int ch = i * 256 + tid;
      const int r = ch >> 3, s = ch & 7;       // K: 1024 chunks of 16B
      gload_lds16(Kp + (size_t)(b * T_ + kv0 + r) * F_ + h * DK_ + ((s ^ (r & 7)) * 8),
                  &Ks[buf][(i * 256 + wid * 64) * 8]);
      const int d = ch >> 4, s2 = ch & 15;     // V: 1024 chunks of 16B
      gload_lds16(Vt + ((size_t)bh * DK_ + d) * T_ + kv0 + ((s2 ^ (d & 15)) * 8),
                  &Vs[buf][(i * 256 + wid * 64) * 8]);
    }
    if (wid == 0 && lane < 32)
      gload_lds16(maskf + b * T_ + kv0 + lane * 4, &Ms[buf][0]);
  };

  if (nt > 0) {
    stage(0, 0);
    __syncthreads();

    for (int t = 0; t < nt; ++t) {
      const int cur = t & 1;
      if (t < nt - 1) stage(cur ^ 1, (t + 1) * 128);

      // S^T = K · Q^T, 4 blocks of 32 kv each
      f32x16 sb[4];
      __builtin_amdgcn_s_setprio(1);
#pragma unroll
      for (int n = 0; n < 4; ++n) {
        bf16x8 kf[4];
#pragma unroll
        for (int kk = 0; kk < 4; ++kk)
          kf[kk] = *(const bf16x8*)&Ks[cur][(n * 32 + la) * 64 + ((((kk << 1) | hi) ^ (la & 7)) * 8)];
        f32x16 s = {};
#pragma unroll
        for (int kk = 0; kk < 4; ++kk)
          s = __builtin_amdgcn_mfma_f32_32x32x16_bf16(kf[kk], qf[kk], s, 0, 0, 0);
        sb[n] = s;
      }
      __builtin_amdgcn_s_setprio(0);

      // mask addend, broadcast reads
      f32x4 mfv[4][4];
#pragma unroll
      for (int n = 0; n < 4; ++n)
#pragma unroll
        for (int g = 0; g < 4; ++g)
          mfv[n][g] = *(const f32x4*)&Ms[cur][n * 32 + 8 * g + 4 * hi];

      // row max (raw/unmasked overestimate is valid)
      float mx[16];
#pragma unroll
      for (int r = 0; r < 16; ++r)
        mx[r] = fmaxf(fmaxf(sb[0][r], sb[1][r]), fmaxf(sb[2][r], sb[3][r]));
#pragma unroll
      for (int st = 8; st > 0; st >>= 1)
#pragma unroll
        for (int r = 0; r < st; ++r) mx[r] = fmaxf(mx[r], mx[r + st]);
      const float rmx = fmaxf(mx[0], __shfl_xor(mx[0], 32, 64));

      // defer-max (T13)
      if (!__all(rmx <= mrun + 8.0f)) {
        const float mnew = fmaxf(mrun, rmx);
        const float alpha = __builtin_amdgcn_exp2f(mrun - mnew);
        lrun *= alpha;
#pragma unroll
        for (int m = 0; m < 2; ++m)
#pragma unroll
          for (int r = 0; r < 16; ++r) oacc[m][r] *= alpha;
        mrun = mnew;
      }

      // P = exp2(S + mask - m), in place
#pragma unroll
      for (int n = 0; n < 4; ++n)
#pragma unroll
        for (int r = 0; r < 16; ++r)
          sb[n][r] = __builtin_amdgcn_exp2f((sb[n][r] + mfv[n][r >> 2][r & 3]) - mrun);

      float sm[16];
#pragma unroll
      for (int r = 0; r < 16; ++r)
        sm[r] = (sb[0][r] + sb[1][r]) + (sb[2][r] + sb[3][r]);
#pragma unroll
      for (int st = 8; st > 0; st >>= 1)
#pragma unroll
        for (int r = 0; r < st; ++r) sm[r] += sm[r + st];
      lrun += sm[0] + __shfl_xor(sm[0], 32, 64);

      // pack P pairs to bf16 words; exchange halves via permlane32_swap
      unsigned lowr[4][2][2], uppr[4][2][2];
#pragma unroll
      for (int n = 0; n < 4; ++n)
#pragma unroll
        for (int gg = 0; gg < 2; ++gg)
#pragma unroll
          for (int hh = 0; hh < 2; ++hh) {
            unsigned xE = cvtpk(sb[n][4 * (2 * gg) + 2 * hh], sb[n][4 * (2 * gg) + 2 * hh + 1]);
            unsigned xO = cvtpk(sb[n][4 * (2 * gg + 1) + 2 * hh], sb[n][4 * (2 * gg + 1) + 2 * hh + 1]);
            asm("v_permlane32_swap_b32 %0, %1" : "+v"(xE), "+v"(xO));
            lowr[n][gg][hh] = xE;
            uppr[n][gg][hh] = xO;
          }

      // O^T += V^T · P^T  (8 kv chunks of 16)
#pragma unroll
      for (int kt = 0; kt < 8; ++kt) {
        const int n = kt >> 1, gg = kt & 1;
        union { unsigned w[4]; bf16x8 v; } pf;
        pf.w[0] = lowr[n][gg][0]; pf.w[1] = lowr[n][gg][1];
        pf.w[2] = uppr[n][gg][0]; pf.w[3] = uppr[n][gg][1];
        __builtin_amdgcn_s_setprio(1);
#pragma unroll
        for (int m = 0; m < 2; ++m) {
          const int d = m * 32 + la;
          bf16x8 vfr = *(const bf16x8*)&Vs[cur][d * 128 + ((((kt << 1) | hi) ^ (d & 15)) * 8)];
          oacc[m] = __builtin_amdgcn_mfma_f32_32x32x16_bf16(vfr, pf.v, oacc[m], 0, 0, 0);
        }
        __builtin_amdgcn_s_setprio(0);
      }
      __syncthreads();
    }
  }

  const float inv = 1.0f / fmaxf(lrun, 1e-37f);
#pragma unroll
  for (int m = 0; m < 2; ++m)
#pragma unroll
    for (int g = 0; g < 4; ++g) {
      union { unsigned short u[4]; s16x4 v; } ov;
#pragma unroll
      for (int j = 0; j < 4; ++j) ov.u[j] = f2bf(oacc[m][4 * g + j] * inv);
      *(s16x4*)(X + (size_t)(b * T_ + qrow) * F_ + h * DK_ + m * 32 + 8 * g + 4 * hi) = ov.v;
    }
}

// ---------------- launcher ----------------
extern "C" void kernel_launch(void* const* d_in, const int* in_sizes, int n_in,
                              void* d_out, int out_size, void* d_ws, size_t ws_size,
                              hipStream_t stream) {
  const float* q  = (const float*)d_in[0];
  const float* k  = (const float*)d_in[1];
  const float* v  = (const float*)d_in[2];
  const int* mask = (const int*)d_in[3];
  const float* Wq = (const float*)d_in[4];
  const float* bq = (const float*)d_in[5];
  const float* Wk = (const float*)d_in[6];
  const float* bk = (const float*)d_in[7];
  const float* Wv = (const float*)d_in[8];
  const float* bv = (const float*)d_in[9];
  const float* Wo = (const float*)d_in[10];
  const float* bo = (const float*)d_in[11];
  float* out = (float*)d_out;

  unsigned short* ws = (unsigned short*)d_ws;
  unsigned short* wts   = ws;                               // 4*F*F = 1,048,576 us
  unsigned short* projq = wts + (size_t)4 * F_ * F_;        // BT*F (Q)
  unsigned short* kc    = projq + (size_t)BT_ * F_;         // BT*F (compacted K)
  unsigned short* vt    = kc + (size_t)BT_ * F_;            // BT*F (compacted V^T per head)
  unsigned short* xbuf  = vt + (size_t)BT_ * F_;            // BT*F (attn output)
  float* maskf = (float*)(xbuf + (size_t)BT_ * F_);         // B*T f32
  int* invidx  = (int*)(maskf + BT_);                       // B*T int
  int* nbuf    = invidx + BT_;                              // B int

  const float kQScale = 0.18033688011112042f;  // (1/sqrt(64)) * log2(e)

  convert_scan<<<dim3(128, 5, 1), 256, 0, stream>>>(
      Wq, Wk, Wv, Wo, mask, wts, invidx, nbuf, maskf);
  gemm_qkv<<<dim3(768, 1, 1), 256, 0, stream>>>(
      q, k, v, wts, bq, bk, bv, invidx, nbuf, projq, kc, vt, kQScale);
  attn_kernel<<<dim3(512, 1, 1), 256, 0, stream>>>(
      projq, kc, vt, maskf, nbuf, xbuf);
  gemm_out<<<dim3(256, 1, 1), 256, 0, stream>>>(
      xbuf, wts + (size_t)3 * F_ * F_, bo, out);
}